// Round 1
// baseline (118341.846 us; speedup 1.0000x reference)
//
#include <hip/hip_runtime.h>
#include <hip/hip_cooperative_groups.h>

namespace cg = cooperative_groups;

#define BB 256
#define SS 512
#define EE 512
#define HH 512
#define G4 2048
#define NTF 799

__device__ __forceinline__ float my_sig(float x) {
    return 1.0f / (1.0f + __expf(-x));
}
__device__ __forceinline__ float my_tanh(float x) {
    float e = __expf(2.0f * x);
    return 1.0f - 2.0f / (e + 1.0f);
}

// Persistent LSTM kernel: grid 256 blocks x 256 threads.
// Block decomposition: rg = bid>>6 (4 row groups of 64 rows), cg = bid&63 (64 col
// groups of 8 h-cols). Each block computes gates (all 4) + cs1 for its tile, then
// updates h/c/hsum for its tile. h/c double-buffered; one grid.sync() per step.
__global__ void __launch_bounds__(256)
lstm_persistent(const float* __restrict__ x,     // [B,S,E]
                const float* __restrict__ ts,    // [B,S]
                const float* __restrict__ Wall,  // [512,2048]
                const float* __restrict__ ball,  // [2048]
                const float* __restrict__ Uall,  // [512,2048]
                const float* __restrict__ bu,    // [2048]
                const float* __restrict__ Wd,    // [512,512]
                const float* __restrict__ bd,    // [512]
                float* __restrict__ h0, float* __restrict__ h1,
                float* __restrict__ c0, float* __restrict__ c1,
                float* __restrict__ hsum,
                float* __restrict__ tsT)         // [512,256] transposed timestamps
{
    cg::grid_group grid = cg::this_grid();
    const int tid = threadIdx.x;
    const int bid = blockIdx.x;
    const int gtid = bid * 256 + tid;

    // ---- init: zero h0/c0/hsum, transpose ts ----
    for (int i = gtid; i < BB * HH; i += 65536) { h0[i] = 0.f; c0[i] = 0.f; hsum[i] = 0.f; }
    for (int i = gtid; i < BB * SS; i += 65536) {
        int b = i >> 9, s = i & 511;
        tsT[s * BB + b] = ts[i];
    }
    grid.sync();

    const int rg  = bid >> 6;
    const int cgi = bid & 63;
    const int r0  = rg << 6;   // 64 rows
    const int m0  = cgi << 3;  // 8 h-cols

    __shared__ float a_t[32][68];   // K-slice x rows (transposed), 16B-aligned rows-of-8
    __shared__ float b_t[32][33];   // K-slice x 32 gate cols
    __shared__ float b2t[32][9];    // K-slice x 8 Wd cols
    __shared__ float gls[64][33];   // sigmoid(gates) tile
    __shared__ float csl[64][9];    // tanh(cs1) tile

    const int j    = tid & 31;            // gate col 0..31  (g = j>>3, mj = j&7)
    const int rgrp = tid >> 5;            // 0..7 -> rows rgrp*8..+7
    const int gcol = ((j >> 3) << 9) + m0 + (j & 7);
    const float bias  = ball[gcol] + bu[gcol];

    const int j2    = tid & 7;            // Wd col
    const int rgrp2 = tid >> 3;           // 0..31 -> rows rgrp2*2..+1
    const float bias2 = bd[m0 + j2];

    for (int s = 0; s < SS; ++s) {
        const float* hp = (s & 1) ? h1 : h0;
        const float* cp = (s & 1) ? c1 : c0;
        float* hn = (s & 1) ? h0 : h1;
        float* cn = (s & 1) ? c0 : c1;

        // ---- GEMM1: gate tile [64 rows x 32 gate cols], K = 1024 over [h | x_s] ----
        float acc[8];
#pragma unroll
        for (int i = 0; i < 8; ++i) acc[i] = bias;

        for (int kt = 0; kt < 32; ++kt) {
            const int k0 = kt << 5;
            __syncthreads();
#pragma unroll
            for (int q = 0; q < 8; ++q) {   // stage a_t[kk][row]
                int lin = tid + (q << 8);
                int kk = lin & 31, row = lin >> 5;
                float v;
                if (k0 < 512) v = hp[(r0 + row) * HH + k0 + kk];
                else v = x[(size_t)(r0 + row) * (SS * EE) + (size_t)s * EE + (k0 - 512) + kk];
                a_t[kk][row] = v;
            }
#pragma unroll
            for (int q = 0; q < 4; ++q) {   // stage b_t[kk][j]
                int lin = tid + (q << 8);
                int kk = lin >> 5, jj = lin & 31;
                int col = ((jj >> 3) << 9) + m0 + (jj & 7);
                float v;
                if (k0 < 512) v = Wall[(k0 + kk) * G4 + col];
                else          v = Uall[(k0 - 512 + kk) * G4 + col];
                b_t[kk][jj] = v;
            }
            __syncthreads();
#pragma unroll
            for (int kk = 0; kk < 32; ++kk) {
                float bv = b_t[kk][j];
                const float* ap = &a_t[kk][rgrp << 3];
#pragma unroll
                for (int i = 0; i < 8; ++i) acc[i] += ap[i] * bv;
            }
        }

        // ---- GEMM2: cs1 tile [64 rows x 8 cols], K = 512 over c ----
        float acc2[2] = { bias2, bias2 };
        for (int kt = 0; kt < 16; ++kt) {
            const int k0 = kt << 5;
            __syncthreads();
#pragma unroll
            for (int q = 0; q < 8; ++q) {
                int lin = tid + (q << 8);
                int kk = lin & 31, row = lin >> 5;
                a_t[kk][row] = cp[(r0 + row) * HH + k0 + kk];
            }
            {
                int kk = tid >> 3, jj = tid & 7;
                b2t[kk][jj] = Wd[(k0 + kk) * HH + m0 + jj];
            }
            __syncthreads();
#pragma unroll
            for (int kk = 0; kk < 32; ++kk) {
                float bv = b2t[kk][j2];
                const float* ap = &a_t[kk][rgrp2 << 1];
                acc2[0] += ap[0] * bv;
                acc2[1] += ap[1] * bv;
            }
        }

        // ---- write activated tiles to LDS for re-partition ----
#pragma unroll
        for (int i = 0; i < 8; ++i)
            gls[(rgrp << 3) + i][j] = my_sig(acc[i]);
#pragma unroll
        for (int i = 0; i < 2; ++i)
            csl[(rgrp2 << 1) + i][j2] = my_tanh(acc2[i]);
        __syncthreads();

        // ---- state update: 64 rows x 8 cols = 512 elems, 2 per thread ----
#pragma unroll
        for (int q = 0; q < 2; ++q) {
            int e = tid + (q << 8);
            int rl = e >> 3, mj = e & 7;
            float f  = gls[rl][mj];
            float ii = gls[rl][8 + mj];
            float oo = gls[rl][16 + mj];
            float ct = gls[rl][24 + mj];
            float c1v = csl[rl][mj];
            float tv  = tsT[s * BB + r0 + rl];
            int gidx = (r0 + rl) * HH + m0 + mj;
            float cold = cp[gidx];
            float cadj = cold + c1v * (tv - 1.0f);
            float cnew = f * cadj + ii * ct;
            float hnew = oo * my_tanh(cnew);
            cn[gidx] = cnew;
            hn[gidx] = hnew;
            hsum[gidx] += hnew;
        }
        grid.sync();
    }
}

// Tail: sub = relu(tfidf@fcw+b); x = [sub | hsum/512]; 3-layer MLP. 1 block per row.
__global__ void __launch_bounds__(256)
tail_kernel(const float* __restrict__ tfidf, const float* __restrict__ hsum,
            const float* __restrict__ fcw, const float* __restrict__ fcb,
            const float* __restrict__ l1w, const float* __restrict__ l1b,
            const float* __restrict__ l2w, const float* __restrict__ l2b,
            const float* __restrict__ low, const float* __restrict__ lob,
            float* __restrict__ out)
{
    const int row = blockIdx.x;
    const int t = threadIdx.x;
    __shared__ float tf[800];
    __shared__ float xrow[1024];
    __shared__ float y1[256];
    __shared__ float y2[128];

    for (int k = t; k < NTF; k += 256) tf[k] = tfidf[row * NTF + k];
    __syncthreads();

    for (int n = t; n < 512; n += 256) {
        float acc = fcb[n];
        for (int k = 0; k < NTF; ++k) acc += tf[k] * fcw[k * 512 + n];
        xrow[n] = fmaxf(acc, 0.f);
    }
    for (int n = t; n < 512; n += 256)
        xrow[512 + n] = hsum[row * HH + n] * (1.0f / 512.0f);
    __syncthreads();

    {
        float acc = l1b[t];
        for (int k = 0; k < 1024; ++k) acc += xrow[k] * l1w[k * 256 + t];
        y1[t] = fmaxf(acc, 0.f);
    }
    __syncthreads();
    if (t < 128) {
        float acc = l2b[t];
        for (int k = 0; k < 256; ++k) acc += y1[k] * l2w[k * 128 + t];
        y2[t] = fmaxf(acc, 0.f);
    }
    __syncthreads();
    if (t < 2) {
        float acc = lob[t];
        for (int k = 0; k < 128; ++k) acc += y2[k] * low[k * 2 + t];
        out[row * 2 + t] = acc;
    }
}

extern "C" void kernel_launch(void* const* d_in, const int* in_sizes, int n_in,
                              void* d_out, int out_size, void* d_ws, size_t ws_size,
                              hipStream_t stream)
{
    const float* x     = (const float*)d_in[0];
    const float* ts    = (const float*)d_in[1];
    const float* tfidf = (const float*)d_in[2];
    const float* Wall  = (const float*)d_in[3];
    const float* ball  = (const float*)d_in[4];
    const float* Uall  = (const float*)d_in[5];
    const float* bu    = (const float*)d_in[6];
    const float* Wd    = (const float*)d_in[7];
    const float* bd    = (const float*)d_in[8];
    const float* fcw   = (const float*)d_in[9];
    const float* fcb   = (const float*)d_in[10];
    const float* l1w   = (const float*)d_in[11];
    const float* l1b   = (const float*)d_in[12];
    const float* l2w   = (const float*)d_in[13];
    const float* l2b   = (const float*)d_in[14];
    const float* low   = (const float*)d_in[15];
    const float* lob   = (const float*)d_in[16];
    float* out = (float*)d_out;

    float* ws  = (float*)d_ws;
    float* h0  = ws;
    float* h1  = h0 + BB * HH;
    float* c0  = h1 + BB * HH;
    float* c1  = c0 + BB * HH;
    float* hs  = c1 + BB * HH;
    float* tsT = hs + BB * HH;   // 512*256 floats; total ws use = 3 MB

    void* args[] = { (void*)&x, (void*)&ts, (void*)&Wall, (void*)&ball, (void*)&Uall,
                     (void*)&bu, (void*)&Wd, (void*)&bd,
                     (void*)&h0, (void*)&h1, (void*)&c0, (void*)&c1,
                     (void*)&hs, (void*)&tsT };
    hipLaunchCooperativeKernel((void*)lstm_persistent, dim3(256), dim3(256), args, 0, stream);

    tail_kernel<<<256, 256, 0, stream>>>(tfidf, hs, fcw, fcb, l1w, l1b, l2w, l2b,
                                         low, lob, out);
}

// Round 4
// 95357.526 us; speedup vs baseline: 1.2410x; 1.2410x over previous
//
#include <hip/hip_runtime.h>
#include <hip/hip_cooperative_groups.h>

namespace cg = cooperative_groups;

#define BB 256
#define SS 512
#define EE 512
#define HH 512
#define G4 2048
#define NTF 799

__device__ __forceinline__ float my_sig(float v) { return 1.0f / (1.0f + __expf(-v)); }
__device__ __forceinline__ float my_tanh(float v) { float e = __expf(2.0f * v); return 1.0f - 2.0f / (e + 1.0f); }

// ROUND 4 = ROUND 1 (passing) inner loops VERBATIM, with exactly one semantic
// change: the per-step cg::grid.sync() is replaced by a fenced counter barrier
// (agent-scope release/acquire -> L1+L2 wb/inv only; the 256MB MALL stays warm).
// Plus a correctness-neutral bijective XCD relabeling of (rg,cgi).
__global__ void __launch_bounds__(256)
lstm_persistent(const float* __restrict__ x, const float* __restrict__ ts,
                const float* __restrict__ Wall, const float* __restrict__ ball,
                const float* __restrict__ Uall, const float* __restrict__ bu,
                const float* __restrict__ Wd,  const float* __restrict__ bd,
                float* __restrict__ h0, float* __restrict__ h1,
                float* __restrict__ c0, float* __restrict__ c1,
                float* __restrict__ hsum,
                float* __restrict__ tsT,
                unsigned* __restrict__ bar)
{
    cg::grid_group grid = cg::this_grid();
    const int tid = threadIdx.x;
    const int bid = blockIdx.x;
    const int gtid = bid * 256 + tid;

    // ---- init: zero h0/c0/hsum, transpose ts, zero barrier; one cg sync ----
    for (int i = gtid; i < BB * HH; i += 65536) { h0[i] = 0.f; c0[i] = 0.f; hsum[i] = 0.f; }
    for (int i = gtid; i < BB * SS; i += 65536) {
        int b = i >> 9, s = i & 511;
        tsT[s * BB + b] = ts[i];
    }
    if (gtid == 0) *bar = 0u;
    grid.sync();

    // XCD-aware bijective relabeling (perf heuristic only)
    const int xcd = bid & 7, tt = bid >> 3;
    const int cgi = (xcd << 3) | (tt & 7);
    const int rg  = tt >> 3;
    const int r0  = rg << 6;   // 64 rows
    const int m0  = cgi << 3;  // 8 h-cols

    __shared__ float a_t[32][68];
    __shared__ float b_t[32][33];
    __shared__ float b2t[32][9];
    __shared__ float gls[64][33];
    __shared__ float csl[64][9];

    const int j    = tid & 31;
    const int rgrp = tid >> 5;
    const int gcol = ((j >> 3) << 9) + m0 + (j & 7);
    const float bias  = ball[gcol] + bu[gcol];

    const int j2    = tid & 7;
    const int rgrp2 = tid >> 3;
    const float bias2 = bd[m0 + j2];

    for (int s = 0; s < SS; ++s) {
        const float* hp = (s & 1) ? h1 : h0;
        const float* cp = (s & 1) ? c1 : c0;
        float* hn = (s & 1) ? h0 : h1;
        float* cn = (s & 1) ? c0 : c1;

        // ---- GEMM1: gate tile [64 x 32], K = 1024 over [h | x_s] ----
        float acc[8];
#pragma unroll
        for (int i = 0; i < 8; ++i) acc[i] = bias;

        for (int kt = 0; kt < 32; ++kt) {
            const int k0 = kt << 5;
            __syncthreads();
#pragma unroll
            for (int q = 0; q < 8; ++q) {
                int lin = tid + (q << 8);
                int kk = lin & 31, row = lin >> 5;
                float v;
                if (k0 < 512) v = hp[(r0 + row) * HH + k0 + kk];
                else v = x[(size_t)(r0 + row) * (SS * EE) + (size_t)s * EE + (k0 - 512) + kk];
                a_t[kk][row] = v;
            }
#pragma unroll
            for (int q = 0; q < 4; ++q) {
                int lin = tid + (q << 8);
                int kk = lin >> 5, jj = lin & 31;
                int col = ((jj >> 3) << 9) + m0 + (jj & 7);
                float v;
                if (k0 < 512) v = Wall[(k0 + kk) * G4 + col];
                else          v = Uall[(k0 - 512 + kk) * G4 + col];
                b_t[kk][jj] = v;
            }
            __syncthreads();
#pragma unroll
            for (int kk = 0; kk < 32; ++kk) {
                float bv = b_t[kk][j];
                const float* ap = &a_t[kk][rgrp << 3];
#pragma unroll
                for (int i = 0; i < 8; ++i) acc[i] += ap[i] * bv;
            }
        }

        // ---- GEMM2: cs1 tile [64 x 8], K = 512 over c ----
        float acc2[2] = { bias2, bias2 };
        for (int kt = 0; kt < 16; ++kt) {
            const int k0 = kt << 5;
            __syncthreads();
#pragma unroll
            for (int q = 0; q < 8; ++q) {
                int lin = tid + (q << 8);
                int kk = lin & 31, row = lin >> 5;
                a_t[kk][row] = cp[(r0 + row) * HH + k0 + kk];
            }
            {
                int kk = tid >> 3, jj = tid & 7;
                b2t[kk][jj] = Wd[(k0 + kk) * HH + m0 + jj];
            }
            __syncthreads();
#pragma unroll
            for (int kk = 0; kk < 32; ++kk) {
                float bv = b2t[kk][j2];
                const float* ap = &a_t[kk][rgrp2 << 1];
                acc2[0] += ap[0] * bv;
                acc2[1] += ap[1] * bv;
            }
        }

        // ---- write activated tiles to LDS ----
#pragma unroll
        for (int i = 0; i < 8; ++i)
            gls[(rgrp << 3) + i][j] = my_sig(acc[i]);
#pragma unroll
        for (int i = 0; i < 2; ++i)
            csl[(rgrp2 << 1) + i][j2] = my_tanh(acc2[i]);
        __syncthreads();

        // ---- state update ----
#pragma unroll
        for (int q = 0; q < 2; ++q) {
            int e = tid + (q << 8);
            int rl = e >> 3, mj = e & 7;
            float f  = gls[rl][mj];
            float ii = gls[rl][8 + mj];
            float oo = gls[rl][16 + mj];
            float ct = gls[rl][24 + mj];
            float c1v = csl[rl][mj];
            float tv  = tsT[s * BB + r0 + rl];
            int gidx = (r0 + rl) * HH + m0 + mj;
            float cold = cp[gidx];
            float cadj = cold + c1v * (tv - 1.0f);
            float cnew = f * cadj + ii * ct;
            float hnew = oo * my_tanh(cnew);
            cn[gidx] = cnew;
            hn[gidx] = hnew;
            hsum[gidx] += hnew;
        }

        // ---- fenced counter barrier (replaces grid.sync) ----
        // 1) drain this wave's stores to L2; 2) block-level barrier so ALL
        // waves' stores are in L2; 3) tid0: agent release (wbl2 L2->L3 +
        // waitcnt) then relaxed add; spin relaxed until all 256 blocks added;
        // 4) block barrier; 5) ALL threads: agent acquire (inv L1+L2) so
        // next-step loads refetch from the coherent L3.
        asm volatile("s_waitcnt vmcnt(0)" ::: "memory");
        __syncthreads();
        if (tid == 0) {
            __builtin_amdgcn_fence(__ATOMIC_RELEASE, "agent");
            __hip_atomic_fetch_add(bar, 1u, __ATOMIC_RELAXED, __HIP_MEMORY_SCOPE_AGENT);
            const unsigned tgt = (unsigned)(s + 1) * 256u;
            while (__hip_atomic_load(bar, __ATOMIC_RELAXED, __HIP_MEMORY_SCOPE_AGENT) < tgt)
                __builtin_amdgcn_s_sleep(8);
        }
        __syncthreads();
        __builtin_amdgcn_fence(__ATOMIC_ACQUIRE, "agent");
    }
}

// Tail: sub = relu(tfidf@fcw+b); x = [sub | hsum/512]; 3-layer MLP. 1 block per row.
__global__ void __launch_bounds__(256)
tail_kernel(const float* __restrict__ tfidf, const float* __restrict__ hsum,
            const float* __restrict__ fcw, const float* __restrict__ fcb,
            const float* __restrict__ l1w, const float* __restrict__ l1b,
            const float* __restrict__ l2w, const float* __restrict__ l2b,
            const float* __restrict__ low, const float* __restrict__ lob,
            float* __restrict__ out)
{
    const int row = blockIdx.x;
    const int t = threadIdx.x;
    __shared__ float tf[800];
    __shared__ float xrow[1024];
    __shared__ float y1[256];
    __shared__ float y2[128];

    for (int k = t; k < NTF; k += 256) tf[k] = tfidf[row * NTF + k];
    __syncthreads();

    for (int n = t; n < 512; n += 256) {
        float acc = fcb[n];
        for (int k = 0; k < NTF; ++k) acc += tf[k] * fcw[k * 512 + n];
        xrow[n] = fmaxf(acc, 0.f);
    }
    for (int n = t; n < 512; n += 256)
        xrow[512 + n] = hsum[row * HH + n] * (1.0f / 512.0f);
    __syncthreads();

    {
        float acc = l1b[t];
        for (int k = 0; k < 1024; ++k) acc += xrow[k] * l1w[k * 256 + t];
        y1[t] = fmaxf(acc, 0.f);
    }
    __syncthreads();
    if (t < 128) {
        float acc = l2b[t];
        for (int k = 0; k < 256; ++k) acc += y1[k] * l2w[k * 128 + t];
        y2[t] = fmaxf(acc, 0.f);
    }
    __syncthreads();
    if (t < 2) {
        float acc = lob[t];
        for (int k = 0; k < 128; ++k) acc += y2[k] * low[k * 2 + t];
        out[row * 2 + t] = acc;
    }
}

extern "C" void kernel_launch(void* const* d_in, const int* in_sizes, int n_in,
                              void* d_out, int out_size, void* d_ws, size_t ws_size,
                              hipStream_t stream)
{
    const float* x     = (const float*)d_in[0];
    const float* ts    = (const float*)d_in[1];
    const float* tfidf = (const float*)d_in[2];
    const float* Wall  = (const float*)d_in[3];
    const float* ball  = (const float*)d_in[4];
    const float* Uall  = (const float*)d_in[5];
    const float* bu    = (const float*)d_in[6];
    const float* Wd    = (const float*)d_in[7];
    const float* bd    = (const float*)d_in[8];
    const float* fcw   = (const float*)d_in[9];
    const float* fcb   = (const float*)d_in[10];
    const float* l1w   = (const float*)d_in[11];
    const float* l1b   = (const float*)d_in[12];
    const float* l2w   = (const float*)d_in[13];
    const float* l2b   = (const float*)d_in[14];
    const float* low   = (const float*)d_in[15];
    const float* lob   = (const float*)d_in[16];
    float* out = (float*)d_out;

    float* ws  = (float*)d_ws;
    float* h0  = ws;
    float* h1  = h0 + BB * HH;
    float* c0  = h1 + BB * HH;
    float* c1  = c0 + BB * HH;
    float* hs  = c1 + BB * HH;
    float* tsT = hs + BB * HH;
    unsigned* bar = (unsigned*)(tsT + BB * SS);

    void* args[] = { (void*)&x, (void*)&ts, (void*)&Wall, (void*)&ball, (void*)&Uall,
                     (void*)&bu, (void*)&Wd, (void*)&bd,
                     (void*)&h0, (void*)&h1, (void*)&c0, (void*)&c1,
                     (void*)&hs, (void*)&tsT, (void*)&bar };
    hipLaunchCooperativeKernel((void*)lstm_persistent, dim3(256), dim3(256), args, 0, stream);

    tail_kernel<<<256, 256, 0, stream>>>(tfidf, hs, fcw, fcb, l1w, l1b, l2w, l2b,
                                         low, lob, out);
}

// Round 5
// 95055.035 us; speedup vs baseline: 1.2450x; 1.0032x over previous
//
#include <hip/hip_runtime.h>
#include <hip/hip_cooperative_groups.h>

namespace cg = cooperative_groups;

#define BB 256
#define SS 512
#define EE 512
#define HH 512
#define G4 2048
#define NTF 799

__device__ __forceinline__ float my_sig(float v) { return 1.0f / (1.0f + __expf(-v)); }
__device__ __forceinline__ float my_tanh(float v) { float e = __expf(2.0f * v); return 1.0f - 2.0f / (e + 1.0f); }

// Agent-coherent access for the ONLY cross-block data (h, c): relaxed
// agent-scope atomics compile to sc1 loads/stores -> coherent at L3,
// bypassing potentially-stale L1/L2 lines. Everything else (weights, x,
// tsT, hsum) is read-only or block-private, so with NO acquire-inv in the
// barrier those lines stay L2-resident across all 512 steps.
__device__ __forceinline__ float ld_dev(const float* p) {
    return __hip_atomic_load(p, __ATOMIC_RELAXED, __HIP_MEMORY_SCOPE_AGENT);
}
__device__ __forceinline__ void st_dev(float* p, float v) {
    __hip_atomic_store(p, v, __ATOMIC_RELAXED, __HIP_MEMORY_SCOPE_AGENT);
}

// ROUND 5 = ROUND 4 (passing) compute structure VERBATIM; only the coherence
// protocol changes: h/c via sc1 atomics, barrier keeps the release fence
// (buffer_wbl2 + waitcnt: writeback, no invalidate) but drops the acquire
// fence entirely -> L2 never invalidated -> weights stay L2-hot.
__global__ void __launch_bounds__(256)
lstm_persistent(const float* __restrict__ x, const float* __restrict__ ts,
                const float* __restrict__ Wall, const float* __restrict__ ball,
                const float* __restrict__ Uall, const float* __restrict__ bu,
                const float* __restrict__ Wd,  const float* __restrict__ bd,
                float* __restrict__ h0, float* __restrict__ h1,
                float* __restrict__ c0, float* __restrict__ c1,
                float* __restrict__ hsum,
                float* __restrict__ tsT,
                unsigned* __restrict__ bar)
{
    cg::grid_group grid = cg::this_grid();
    const int tid = threadIdx.x;
    const int bid = blockIdx.x;
    const int gtid = bid * 256 + tid;

    // ---- init: zero h0/c0/hsum, transpose ts, zero barrier; one cg sync ----
    for (int i = gtid; i < BB * HH; i += 65536) { h0[i] = 0.f; c0[i] = 0.f; hsum[i] = 0.f; }
    for (int i = gtid; i < BB * SS; i += 65536) {
        int b = i >> 9, s = i & 511;
        tsT[s * BB + b] = ts[i];
    }
    if (gtid == 0) *bar = 0u;
    grid.sync();

    // XCD-aware bijective relabeling (perf heuristic only)
    const int xcd = bid & 7, tt = bid >> 3;
    const int cgi = (xcd << 3) | (tt & 7);
    const int rg  = tt >> 3;
    const int r0  = rg << 6;   // 64 rows
    const int m0  = cgi << 3;  // 8 h-cols

    __shared__ float a_t[32][68];
    __shared__ float b_t[32][33];
    __shared__ float b2t[32][9];
    __shared__ float gls[64][33];
    __shared__ float csl[64][9];

    const int j    = tid & 31;
    const int rgrp = tid >> 5;
    const int gcol = ((j >> 3) << 9) + m0 + (j & 7);
    const float bias  = ball[gcol] + bu[gcol];

    const int j2    = tid & 7;
    const int rgrp2 = tid >> 3;
    const float bias2 = bd[m0 + j2];

    for (int s = 0; s < SS; ++s) {
        const float* hp = (s & 1) ? h1 : h0;
        const float* cp = (s & 1) ? c1 : c0;
        float* hn = (s & 1) ? h0 : h1;
        float* cn = (s & 1) ? c0 : c1;

        // ---- GEMM1: gate tile [64 x 32], K = 1024 over [h | x_s] ----
        float acc[8];
#pragma unroll
        for (int i = 0; i < 8; ++i) acc[i] = bias;

        for (int kt = 0; kt < 32; ++kt) {
            const int k0 = kt << 5;
            __syncthreads();
#pragma unroll
            for (int q = 0; q < 8; ++q) {
                int lin = tid + (q << 8);
                int kk = lin & 31, row = lin >> 5;
                float v;
                if (k0 < 512) v = ld_dev(&hp[(r0 + row) * HH + k0 + kk]);
                else v = x[(size_t)(r0 + row) * (SS * EE) + (size_t)s * EE + (k0 - 512) + kk];
                a_t[kk][row] = v;
            }
#pragma unroll
            for (int q = 0; q < 4; ++q) {
                int lin = tid + (q << 8);
                int kk = lin >> 5, jj = lin & 31;
                int col = ((jj >> 3) << 9) + m0 + (jj & 7);
                float v;
                if (k0 < 512) v = Wall[(k0 + kk) * G4 + col];
                else          v = Uall[(k0 - 512 + kk) * G4 + col];
                b_t[kk][jj] = v;
            }
            __syncthreads();
#pragma unroll
            for (int kk = 0; kk < 32; ++kk) {
                float bv = b_t[kk][j];
                const float* ap = &a_t[kk][rgrp << 3];
#pragma unroll
                for (int i = 0; i < 8; ++i) acc[i] += ap[i] * bv;
            }
        }

        // ---- GEMM2: cs1 tile [64 x 8], K = 512 over c ----
        float acc2[2] = { bias2, bias2 };
        for (int kt = 0; kt < 16; ++kt) {
            const int k0 = kt << 5;
            __syncthreads();
#pragma unroll
            for (int q = 0; q < 8; ++q) {
                int lin = tid + (q << 8);
                int kk = lin & 31, row = lin >> 5;
                a_t[kk][row] = ld_dev(&cp[(r0 + row) * HH + k0 + kk]);
            }
            {
                int kk = tid >> 3, jj = tid & 7;
                b2t[kk][jj] = Wd[(k0 + kk) * HH + m0 + jj];
            }
            __syncthreads();
#pragma unroll
            for (int kk = 0; kk < 32; ++kk) {
                float bv = b2t[kk][j2];
                const float* ap = &a_t[kk][rgrp2 << 1];
                acc2[0] += ap[0] * bv;
                acc2[1] += ap[1] * bv;
            }
        }

        // ---- write activated tiles to LDS ----
#pragma unroll
        for (int i = 0; i < 8; ++i)
            gls[(rgrp << 3) + i][j] = my_sig(acc[i]);
#pragma unroll
        for (int i = 0; i < 2; ++i)
            csl[(rgrp2 << 1) + i][j2] = my_tanh(acc2[i]);
        __syncthreads();

        // ---- state update ----
#pragma unroll
        for (int q = 0; q < 2; ++q) {
            int e = tid + (q << 8);
            int rl = e >> 3, mj = e & 7;
            float f  = gls[rl][mj];
            float ii = gls[rl][8 + mj];
            float oo = gls[rl][16 + mj];
            float ct = gls[rl][24 + mj];
            float c1v = csl[rl][mj];
            float tv  = tsT[s * BB + r0 + rl];
            int gidx = (r0 + rl) * HH + m0 + mj;
            float cold = ld_dev(&cp[gidx]);   // sc1: own tile was sc1-stored, L2 line would be stale
            float cadj = cold + c1v * (tv - 1.0f);
            float cnew = f * cadj + ii * ct;
            float hnew = oo * my_tanh(cnew);
            st_dev(&cn[gidx], cnew);
            st_dev(&hn[gidx], hnew);
            hsum[gidx] += hnew;               // block-private: plain RMW, stays in local L2
        }

        // ---- fenced counter barrier: release (wbl2, NO inv) + relaxed spin ----
        asm volatile("s_waitcnt vmcnt(0)" ::: "memory");
        __syncthreads();
        if (tid == 0) {
            __builtin_amdgcn_fence(__ATOMIC_RELEASE, "agent");  // buffer_wbl2 sc1 + waitcnt: drain to L3
            __hip_atomic_fetch_add(bar, 1u, __ATOMIC_RELAXED, __HIP_MEMORY_SCOPE_AGENT);
            const unsigned tgt = (unsigned)(s + 1) * 256u;
            while (__hip_atomic_load(bar, __ATOMIC_RELAXED, __HIP_MEMORY_SCOPE_AGENT) < tgt)
                __builtin_amdgcn_s_sleep(8);
        }
        __syncthreads();
        // NO acquire fence: h/c reads are sc1 (L3-coherent by themselves);
        // weights/x/tsT are read-only, hsum block-private -> L2 stays warm.
    }
}

// Tail: sub = relu(tfidf@fcw+b); x = [sub | hsum/512]; 3-layer MLP. 1 block per row.
__global__ void __launch_bounds__(256)
tail_kernel(const float* __restrict__ tfidf, const float* __restrict__ hsum,
            const float* __restrict__ fcw, const float* __restrict__ fcb,
            const float* __restrict__ l1w, const float* __restrict__ l1b,
            const float* __restrict__ l2w, const float* __restrict__ l2b,
            const float* __restrict__ low, const float* __restrict__ lob,
            float* __restrict__ out)
{
    const int row = blockIdx.x;
    const int t = threadIdx.x;
    __shared__ float tf[800];
    __shared__ float xrow[1024];
    __shared__ float y1[256];
    __shared__ float y2[128];

    for (int k = t; k < NTF; k += 256) tf[k] = tfidf[row * NTF + k];
    __syncthreads();

    for (int n = t; n < 512; n += 256) {
        float acc = fcb[n];
        for (int k = 0; k < NTF; ++k) acc += tf[k] * fcw[k * 512 + n];
        xrow[n] = fmaxf(acc, 0.f);
    }
    for (int n = t; n < 512; n += 256)
        xrow[512 + n] = hsum[row * HH + n] * (1.0f / 512.0f);
    __syncthreads();

    {
        float acc = l1b[t];
        for (int k = 0; k < 1024; ++k) acc += xrow[k] * l1w[k * 256 + t];
        y1[t] = fmaxf(acc, 0.f);
    }
    __syncthreads();
    if (t < 128) {
        float acc = l2b[t];
        for (int k = 0; k < 256; ++k) acc += y1[k] * l2w[k * 128 + t];
        y2[t] = fmaxf(acc, 0.f);
    }
    __syncthreads();
    if (t < 2) {
        float acc = lob[t];
        for (int k = 0; k < 128; ++k) acc += y2[k] * low[k * 2 + t];
        out[row * 2 + t] = acc;
    }
}

extern "C" void kernel_launch(void* const* d_in, const int* in_sizes, int n_in,
                              void* d_out, int out_size, void* d_ws, size_t ws_size,
                              hipStream_t stream)
{
    const float* x     = (const float*)d_in[0];
    const float* ts    = (const float*)d_in[1];
    const float* tfidf = (const float*)d_in[2];
    const float* Wall  = (const float*)d_in[3];
    const float* ball  = (const float*)d_in[4];
    const float* Uall  = (const float*)d_in[5];
    const float* bu    = (const float*)d_in[6];
    const float* Wd    = (const float*)d_in[7];
    const float* bd    = (const float*)d_in[8];
    const float* fcw   = (const float*)d_in[9];
    const float* fcb   = (const float*)d_in[10];
    const float* l1w   = (const float*)d_in[11];
    const float* l1b   = (const float*)d_in[12];
    const float* l2w   = (const float*)d_in[13];
    const float* l2b   = (const float*)d_in[14];
    const float* low   = (const float*)d_in[15];
    const float* lob   = (const float*)d_in[16];
    float* out = (float*)d_out;

    float* ws  = (float*)d_ws;
    float* h0  = ws;
    float* h1  = h0 + BB * HH;
    float* c0  = h1 + BB * HH;
    float* c1  = c0 + BB * HH;
    float* hs  = c1 + BB * HH;
    float* tsT = hs + BB * HH;
    unsigned* bar = (unsigned*)(tsT + BB * SS);

    void* args[] = { (void*)&x, (void*)&ts, (void*)&Wall, (void*)&ball, (void*)&Uall,
                     (void*)&bu, (void*)&Wd, (void*)&bd,
                     (void*)&h0, (void*)&h1, (void*)&c0, (void*)&c1,
                     (void*)&hs, (void*)&tsT, (void*)&bar };
    hipLaunchCooperativeKernel((void*)lstm_persistent, dim3(256), dim3(256), args, 0, stream);

    tail_kernel<<<256, 256, 0, stream>>>(tfidf, hs, fcw, fcb, l1w, l1b, l2w, l2b,
                                         low, lob, out);
}

// Round 6
// 30214.505 us; speedup vs baseline: 3.9167x; 3.1460x over previous
//
#include <hip/hip_runtime.h>
#include <hip/hip_cooperative_groups.h>

namespace cg = cooperative_groups;

#define BB 256
#define SS 512
#define EE 512
#define HH 512
#define G4 2048
#define NTF 799

__device__ __forceinline__ float my_sig(float v) { return 1.0f / (1.0f + __expf(-v)); }
__device__ __forceinline__ float my_tanh(float v) { float e = __expf(2.0f * v); return 1.0f - 2.0f / (e + 1.0f); }

// Verified (rounds 4+5) coherence protocol: h/c cross-block state via relaxed
// agent-scope (sc1) atomics -> L3-coherent; barrier has release fence only
// (writeback, no invalidate) so weights/x stay L2-resident all 512 steps.
__device__ __forceinline__ float ld_dev(const float* p) {
    return __hip_atomic_load(p, __ATOMIC_RELAXED, __HIP_MEMORY_SCOPE_AGENT);
}
__device__ __forceinline__ void st_dev(float* p, float v) {
    __hip_atomic_store(p, v, __ATOMIC_RELAXED, __HIP_MEMORY_SCOPE_AGENT);
}

// ROUND 6 = round-5 protocol + state-update semantics VERBATIM; compute
// structure rebuilt: BK=64 chunks (24 phases/step vs 48), register-pipelined
// prefetch (chunk c+1 loads issued during chunk c compute), 4x2 register tile
// with float4/float2 LDS reads, float4 staging stores. K accumulation order
// identical to round 1 (k ascending) -> bitwise-same results expected.
__global__ void __launch_bounds__(256)
lstm_persistent(const float* __restrict__ x, const float* __restrict__ ts,
                const float* __restrict__ Wall, const float* __restrict__ ball,
                const float* __restrict__ Uall, const float* __restrict__ bu,
                const float* __restrict__ Wd,  const float* __restrict__ bd,
                float* __restrict__ h0, float* __restrict__ h1,
                float* __restrict__ c0, float* __restrict__ c1,
                float* __restrict__ hsum,
                float* __restrict__ tsT,
                unsigned* __restrict__ bar)
{
    cg::grid_group grid = cg::this_grid();
    const int tid = threadIdx.x;
    const int bid = blockIdx.x;
    const int gtid = bid * 256 + tid;

    // ---- init: zero h0/c0/hsum, transpose ts, zero barrier; one cg sync ----
    for (int i = gtid; i < BB * HH; i += 65536) { h0[i] = 0.f; c0[i] = 0.f; hsum[i] = 0.f; }
    for (int i = gtid; i < BB * SS; i += 65536) {
        int b = i >> 9, s = i & 511;
        tsT[s * BB + b] = ts[i];
    }
    if (gtid == 0) *bar = 0u;
    grid.sync();

    // XCD-aware bijective relabeling (perf heuristic only)
    const int xcd = bid & 7, tt = bid >> 3;
    const int cgi = (xcd << 3) | (tt & 7);
    const int rg  = tt >> 3;
    const int r0  = rg << 6;   // 64 rows
    const int m0  = cgi << 3;  // 8 h-cols

    __shared__ __align__(16) float a_t[64][68];   // K-slice x 64 rows
    __shared__ __align__(16) float b_t[64][34];   // K-slice x 32 gate cols
    __shared__ __align__(16) float b2t[64][10];   // K-slice x 8 Wd cols
    __shared__ __align__(16) float gls[64][34];   // sigmoid(gates)
    __shared__ __align__(16) float csl[64][10];   // tanh(cs1)

    // staging geometry (BK=64): per thread akk fixed, 16 rows in 4 float4 groups
    const int akk   = tid & 63;
    const int arow4 = (tid >> 6) << 2;   // {0,4,8,12}; rows = arow4 + 16*g + i
    const int bjj   = tid & 31;          // b_t col; kk = (tid>>5) + 8q
    const int bcol  = ((bjj >> 3) << 9) + m0 + (bjj & 7);
    const int b2jj  = tid & 7;           // b2t col; kk = (tid>>3) + 32q

    // GEMM1 compute mapping: 4 rows x 2 cols per thread
    const int rgrp1 = tid & 15;          // rows 4*rgrp1 .. +3
    const int jp    = tid >> 4;          // cols 2jp, 2jp+1 (of 32)
    const int cj0 = jp << 1, cj1 = cj0 + 1;
    const int gc0 = ((cj0 >> 3) << 9) + m0 + (cj0 & 7);
    const int gc1 = ((cj1 >> 3) << 9) + m0 + (cj1 & 7);
    const float bias0 = ball[gc0] + bu[gc0];
    const float bias1 = ball[gc1] + bu[gc1];

    // GEMM2 compute mapping: 2 rows x 1 col per thread
    const int j2 = tid & 7, rgrp2 = tid >> 3;
    const float bias2 = bd[m0 + j2];

    for (int s = 0; s < SS; ++s) {
        const float* hp = (s & 1) ? h1 : h0;
        const float* cp = (s & 1) ? c1 : c0;
        float* hn = (s & 1) ? h0 : h1;
        float* cn = (s & 1) ? c0 : c1;

        // ================= GEMM1: [64 x 32], K=1024 in 16 chunks of 64 =========
        float a00 = bias0, a01 = bias1, a10 = bias0, a11 = bias1,
              a20 = bias0, a21 = bias1, a30 = bias0, a31 = bias1;
        float ra[16], rb[8];

        // prologue: chunk 0 (k0=0 -> h, Wall)
#pragma unroll
        for (int g = 0; g < 4; ++g)
#pragma unroll
            for (int i = 0; i < 4; ++i)
                ra[4 * g + i] = ld_dev(&hp[(r0 + arow4 + (g << 4) + i) * HH + akk]);
#pragma unroll
        for (int q = 0; q < 8; ++q)
            rb[q] = Wall[((tid >> 5) + (q << 3)) * G4 + bcol];

        for (int c = 0; c < 16; ++c) {
            __syncthreads();
#pragma unroll
            for (int g = 0; g < 4; ++g)
                *(float4*)&a_t[akk][arow4 + (g << 4)] =
                    make_float4(ra[4 * g], ra[4 * g + 1], ra[4 * g + 2], ra[4 * g + 3]);
#pragma unroll
            for (int q = 0; q < 8; ++q)
                b_t[(tid >> 5) + (q << 3)][bjj] = rb[q];
            __syncthreads();

            if (c < 15) {
                const int k0 = (c + 1) << 6;
                if (k0 < 512) {
#pragma unroll
                    for (int g = 0; g < 4; ++g)
#pragma unroll
                        for (int i = 0; i < 4; ++i)
                            ra[4 * g + i] = ld_dev(&hp[(r0 + arow4 + (g << 4) + i) * HH + k0 + akk]);
#pragma unroll
                    for (int q = 0; q < 8; ++q)
                        rb[q] = Wall[(k0 + (tid >> 5) + (q << 3)) * G4 + bcol];
                } else {
#pragma unroll
                    for (int g = 0; g < 4; ++g)
#pragma unroll
                        for (int i = 0; i < 4; ++i)
                            ra[4 * g + i] = x[(size_t)(r0 + arow4 + (g << 4) + i) * (SS * EE)
                                              + (size_t)s * EE + (k0 - 512) + akk];
#pragma unroll
                    for (int q = 0; q < 8; ++q)
                        rb[q] = Uall[(k0 - 512 + (tid >> 5) + (q << 3)) * G4 + bcol];
                }
            }

#pragma unroll 8
            for (int kk = 0; kk < 64; ++kk) {
                const float4 av = *(const float4*)&a_t[kk][rgrp1 << 2];
                const float2 bv = *(const float2*)&b_t[kk][jp << 1];
                a00 += av.x * bv.x; a01 += av.x * bv.y;
                a10 += av.y * bv.x; a11 += av.y * bv.y;
                a20 += av.z * bv.x; a21 += av.z * bv.y;
                a30 += av.w * bv.x; a31 += av.w * bv.y;
            }
        }

        // ================= GEMM2: cs1 [64 x 8], K=512 in 8 chunks of 64 ========
        float g0 = bias2, g1 = bias2;
        float rc[16], rw2[2];

        // prologue (issue loads before the activation stores so they overlap)
#pragma unroll
        for (int g = 0; g < 4; ++g)
#pragma unroll
            for (int i = 0; i < 4; ++i)
                rc[4 * g + i] = ld_dev(&cp[(r0 + arow4 + (g << 4) + i) * HH + akk]);
#pragma unroll
        for (int q = 0; q < 2; ++q)
            rw2[q] = Wd[((tid >> 3) + (q << 5)) * HH + m0 + b2jj];

        {   // write sigmoid(gates) tile (read later at state update)
            const int rb0 = rgrp1 << 2, cc = jp << 1;
            *(float2*)&gls[rb0 + 0][cc] = make_float2(my_sig(a00), my_sig(a01));
            *(float2*)&gls[rb0 + 1][cc] = make_float2(my_sig(a10), my_sig(a11));
            *(float2*)&gls[rb0 + 2][cc] = make_float2(my_sig(a20), my_sig(a21));
            *(float2*)&gls[rb0 + 3][cc] = make_float2(my_sig(a30), my_sig(a31));
        }

        for (int c2 = 0; c2 < 8; ++c2) {
            __syncthreads();
#pragma unroll
            for (int g = 0; g < 4; ++g)
                *(float4*)&a_t[akk][arow4 + (g << 4)] =
                    make_float4(rc[4 * g], rc[4 * g + 1], rc[4 * g + 2], rc[4 * g + 3]);
#pragma unroll
            for (int q = 0; q < 2; ++q)
                b2t[(tid >> 3) + (q << 5)][b2jj] = rw2[q];
            __syncthreads();

            if (c2 < 7) {
                const int k0 = (c2 + 1) << 6;
#pragma unroll
                for (int g = 0; g < 4; ++g)
#pragma unroll
                    for (int i = 0; i < 4; ++i)
                        rc[4 * g + i] = ld_dev(&cp[(r0 + arow4 + (g << 4) + i) * HH + k0 + akk]);
#pragma unroll
                for (int q = 0; q < 2; ++q)
                    rw2[q] = Wd[(k0 + (tid >> 3) + (q << 5)) * HH + m0 + b2jj];
            }

#pragma unroll 8
            for (int kk = 0; kk < 64; ++kk) {
                const float2 av = *(const float2*)&a_t[kk][rgrp2 << 1];
                const float bv = b2t[kk][j2];
                g0 += av.x * bv; g1 += av.y * bv;
            }
        }
        csl[(rgrp2 << 1) + 0][j2] = my_tanh(g0);
        csl[(rgrp2 << 1) + 1][j2] = my_tanh(g1);
        __syncthreads();

        // ---- state update (round-1/5 semantics verbatim) ----
#pragma unroll
        for (int q = 0; q < 2; ++q) {
            int e = tid + (q << 8);
            int rl = e >> 3, mj = e & 7;
            float f  = gls[rl][mj];
            float ii = gls[rl][8 + mj];
            float oo = gls[rl][16 + mj];
            float ct = gls[rl][24 + mj];
            float c1v = csl[rl][mj];
            float tv  = tsT[s * BB + r0 + rl];
            int gidx = (r0 + rl) * HH + m0 + mj;
            float cold = ld_dev(&cp[gidx]);
            float cadj = cold + c1v * (tv - 1.0f);
            float cnew = f * cadj + ii * ct;
            float hnew = oo * my_tanh(cnew);
            st_dev(&cn[gidx], cnew);
            st_dev(&hn[gidx], hnew);
            hsum[gidx] += hnew;
        }

        // ---- fenced counter barrier: release (wbl2, NO inv) + relaxed spin ----
        asm volatile("s_waitcnt vmcnt(0)" ::: "memory");
        __syncthreads();
        if (tid == 0) {
            __builtin_amdgcn_fence(__ATOMIC_RELEASE, "agent");
            __hip_atomic_fetch_add(bar, 1u, __ATOMIC_RELAXED, __HIP_MEMORY_SCOPE_AGENT);
            const unsigned tgt = (unsigned)(s + 1) * 256u;
            while (__hip_atomic_load(bar, __ATOMIC_RELAXED, __HIP_MEMORY_SCOPE_AGENT) < tgt)
                __builtin_amdgcn_s_sleep(8);
        }
        __syncthreads();
    }
}

// Tail: sub = relu(tfidf@fcw+b); x = [sub | hsum/512]; 3-layer MLP. 1 block per row.
__global__ void __launch_bounds__(256)
tail_kernel(const float* __restrict__ tfidf, const float* __restrict__ hsum,
            const float* __restrict__ fcw, const float* __restrict__ fcb,
            const float* __restrict__ l1w, const float* __restrict__ l1b,
            const float* __restrict__ l2w, const float* __restrict__ l2b,
            const float* __restrict__ low, const float* __restrict__ lob,
            float* __restrict__ out)
{
    const int row = blockIdx.x;
    const int t = threadIdx.x;
    __shared__ float tf[800];
    __shared__ float xrow[1024];
    __shared__ float y1[256];
    __shared__ float y2[128];

    for (int k = t; k < NTF; k += 256) tf[k] = tfidf[row * NTF + k];
    __syncthreads();

    for (int n = t; n < 512; n += 256) {
        float acc = fcb[n];
        for (int k = 0; k < NTF; ++k) acc += tf[k] * fcw[k * 512 + n];
        xrow[n] = fmaxf(acc, 0.f);
    }
    for (int n = t; n < 512; n += 256)
        xrow[512 + n] = hsum[row * HH + n] * (1.0f / 512.0f);
    __syncthreads();

    {
        float acc = l1b[t];
        for (int k = 0; k < 1024; ++k) acc += xrow[k] * l1w[k * 256 + t];
        y1[t] = fmaxf(acc, 0.f);
    }
    __syncthreads();
    if (t < 128) {
        float acc = l2b[t];
        for (int k = 0; k < 256; ++k) acc += y1[k] * l2w[k * 128 + t];
        y2[t] = fmaxf(acc, 0.f);
    }
    __syncthreads();
    if (t < 2) {
        float acc = lob[t];
        for (int k = 0; k < 128; ++k) acc += y2[k] * low[k * 2 + t];
        out[row * 2 + t] = acc;
    }
}

extern "C" void kernel_launch(void* const* d_in, const int* in_sizes, int n_in,
                              void* d_out, int out_size, void* d_ws, size_t ws_size,
                              hipStream_t stream)
{
    const float* x     = (const float*)d_in[0];
    const float* ts    = (const float*)d_in[1];
    const float* tfidf = (const float*)d_in[2];
    const float* Wall  = (const float*)d_in[3];
    const float* ball  = (const float*)d_in[4];
    const float* Uall  = (const float*)d_in[5];
    const float* bu    = (const float*)d_in[6];
    const float* Wd    = (const float*)d_in[7];
    const float* bd    = (const float*)d_in[8];
    const float* fcw   = (const float*)d_in[9];
    const float* fcb   = (const float*)d_in[10];
    const float* l1w   = (const float*)d_in[11];
    const float* l1b   = (const float*)d_in[12];
    const float* l2w   = (const float*)d_in[13];
    const float* l2b   = (const float*)d_in[14];
    const float* low   = (const float*)d_in[15];
    const float* lob   = (const float*)d_in[16];
    float* out = (float*)d_out;

    float* ws  = (float*)d_ws;
    float* h0  = ws;
    float* h1  = h0 + BB * HH;
    float* c0  = h1 + BB * HH;
    float* c1  = c0 + BB * HH;
    float* hs  = c1 + BB * HH;
    float* tsT = hs + BB * HH;
    unsigned* bar = (unsigned*)(tsT + BB * SS);

    void* args[] = { (void*)&x, (void*)&ts, (void*)&Wall, (void*)&ball, (void*)&Uall,
                     (void*)&bu, (void*)&Wd, (void*)&bd,
                     (void*)&h0, (void*)&h1, (void*)&c0, (void*)&c1,
                     (void*)&hs, (void*)&tsT, (void*)&bar };
    hipLaunchCooperativeKernel((void*)lstm_persistent, dim3(256), dim3(256), args, 0, stream);

    tail_kernel<<<256, 256, 0, stream>>>(tfidf, hs, fcw, fcb, l1w, l1b, l2w, l2b,
                                         low, lob, out);
}

// Round 7
// 27208.755 us; speedup vs baseline: 4.3494x; 1.1105x over previous
//
#include <hip/hip_runtime.h>
#include <hip/hip_cooperative_groups.h>

namespace cg = cooperative_groups;

#define BB 256
#define SS 512
#define EE 512
#define HH 512
#define G4 2048
#define NTF 799

__device__ __forceinline__ float my_sig(float v) { return 1.0f / (1.0f + __expf(-v)); }
__device__ __forceinline__ float my_tanh(float v) { float e = __expf(2.0f * v); return 1.0f - 2.0f / (e + 1.0f); }

// Verified (r4-r6) protocol: ALL cross-block state (h,c) via relaxed agent-scope
// (sc1) atomics -> coherent at L3, bypassing stale L1/L2. Weights/x/tsT are
// read-only -> L2-resident all 512 steps (no invalidates ever). sc1 stores are
// agent-visible once vmcnt-acked (LLVM emits wbl2 only for fences over PLAIN
// stores), so the barrier needs no fence at all: vmcnt(0) + counter add.
__device__ __forceinline__ float ld_dev(const float* p) {
    return __hip_atomic_load(p, __ATOMIC_RELAXED, __HIP_MEMORY_SCOPE_AGENT);
}
__device__ __forceinline__ void st_dev(float* p, float v) {
    __hip_atomic_store(p, v, __ATOMIC_RELAXED, __HIP_MEMORY_SCOPE_AGENT);
}

// ROUND 7: 512 threads/block (2 waves/SIMD, 2x occupancy). Tile = 32 rows x
// 16 h-cols (64 gate cols). Step order: [x-part GEMM (independent) | barrier |
// h-part GEMM | cs1 GEMM | update] so the barrier + h/c store drain hide under
// 8 chunks of x-compute. c, hsum, cs1 live in registers (1 elem/thread).
__global__ void __launch_bounds__(512)
lstm_persistent(const float* __restrict__ x, const float* __restrict__ ts,
                const float* __restrict__ Wall, const float* __restrict__ ball,
                const float* __restrict__ Uall, const float* __restrict__ bu,
                const float* __restrict__ Wd,  const float* __restrict__ bd,
                float* __restrict__ h0, float* __restrict__ h1,
                float* __restrict__ c0, float* __restrict__ c1,
                float* __restrict__ hsum,
                float* __restrict__ tsT,
                unsigned* __restrict__ bar)
{
    cg::grid_group grid = cg::this_grid();
    const int tid = threadIdx.x;
    const int bid = blockIdx.x;
    const int gtid = (bid << 9) + tid;

    // ---- init: zero h0/c0, transpose ts, zero barrier; one cg sync ----
    for (int i = gtid; i < BB * HH; i += 131072) { h0[i] = 0.f; c0[i] = 0.f; }
    for (int i = gtid; i < BB * SS; i += 131072) {
        int b = i >> 9, s = i & 511;
        tsT[s * BB + b] = ts[i];
    }
    if (gtid == 0) *bar = 0u;
    grid.sync();

    // XCD-aware bijective relabeling (perf heuristic only): 32 blocks/XCD
    // cover 4 cgi x 8 rg -> per-XCD weight slice ~2.1MB stays L2-resident.
    const int xcd = bid & 7, tt = bid >> 3;
    const int cgi = (xcd << 2) | (tt & 3);   // 0..31
    const int rg  = tt >> 2;                 // 0..7
    const int r0  = rg << 5;                 // 32 rows
    const int m0  = cgi << 4;                // 16 h-cols -> 64 gate cols

    __shared__ __align__(16) float a_t[64][36];   // K-slice x 32 rows (+pad)
    __shared__ __align__(16) float b_t[64][68];   // K-slice x 64 gate cols
    __shared__ __align__(16) float b2t[64][20];   // K-slice x 16 Wd cols
    __shared__ __align__(16) float gls[32][68];   // sigmoid(gates)

    // A/c staging: thread -> (akk = K-lane, rows arow..arow+3)
    const int akk  = tid & 63;
    const int arow = (tid >> 6) << 2;        // 0,4,...,28
    // B staging: thread -> (gate col bjj, kk = (q<<3)|kk8)
    const int bjj  = tid & 63;
    const int kk8  = tid >> 6;               // 0..7
    const int bcol = ((bjj >> 4) << 9) + m0 + (bjj & 15);
    // Wd staging: thread -> (col wjj, kk = (q<<5)|wkk)
    const int wjj  = tid & 15;
    const int wkk  = tid >> 4;               // 0..31

    // GEMM1 compute: 2 rows x 2 cols per thread
    const int rgrp = tid & 15;               // rows 2*rgrp, 2*rgrp+1
    const int jp   = tid >> 4;               // cols 2*jp, 2*jp+1 (of 64)
    const int cj0 = jp << 1, cj1 = cj0 + 1;
    const int gc0 = ((cj0 >> 4) << 9) + m0 + (cj0 & 15);
    const int gc1 = ((cj1 >> 4) << 9) + m0 + (cj1 & 15);
    const float bias0 = ball[gc0] + bu[gc0];
    const float bias1 = ball[gc1] + bu[gc1];

    // GEMM2 + update: 1 elem per thread, identity mapping (rl==wkk, mj==wjj)
    const int rl = tid >> 4;                 // 0..31
    const int mj = tid & 15;                 // 0..15
    const float bias2 = bd[m0 + mj];
    float creg = 0.f, hsreg = 0.f;

    for (int s = 0; s < SS; ++s) {
        const float* hp = (s & 1) ? h1 : h0;
        const float* cp = (s & 1) ? c1 : c0;
        float* hn = (s & 1) ? h0 : h1;
        float* cn = (s & 1) ? c0 : c1;

        float a00 = bias0, a01 = bias1, a10 = bias0, a11 = bias1;
        float ra[4], rb[8], rc[4], rw[2];

        // ========== Phase A: x.U part (K=512..1023) — independent of state ====
#pragma unroll
        for (int i = 0; i < 4; ++i)
            ra[i] = x[(size_t)(r0 + arow + i) * (SS * EE) + (size_t)s * EE + akk];
#pragma unroll
        for (int q = 0; q < 8; ++q)
            rb[q] = Uall[((q << 3) | kk8) * G4 + bcol];

        for (int c = 0; c < 8; ++c) {
            __syncthreads();
            *(float4*)&a_t[akk][arow] = make_float4(ra[0], ra[1], ra[2], ra[3]);
#pragma unroll
            for (int q = 0; q < 8; ++q)
                b_t[(q << 3) | kk8][bjj] = rb[q];
            __syncthreads();
            if (c < 7) {
                const int k0 = (c + 1) << 6;
#pragma unroll
                for (int i = 0; i < 4; ++i)
                    ra[i] = x[(size_t)(r0 + arow + i) * (SS * EE) + (size_t)s * EE + k0 + akk];
#pragma unroll
                for (int q = 0; q < 8; ++q)
                    rb[q] = Uall[(k0 + ((q << 3) | kk8)) * G4 + bcol];
            }
#pragma unroll 8
            for (int kk = 0; kk < 64; ++kk) {
                const float2 av = *(const float2*)&a_t[kk][rgrp << 1];
                const float2 bv = *(const float2*)&b_t[kk][jp << 1];
                a00 += av.x * bv.x; a01 += av.x * bv.y;
                a10 += av.y * bv.x; a11 += av.y * bv.y;
            }
        }

        // ========== barrier: h/c(s) ready (stores of s-1 drained long ago) ====
        asm volatile("s_waitcnt vmcnt(0)" ::: "memory");
        __syncthreads();
        if (tid == 0) {
            __hip_atomic_fetch_add(bar, 1u, __ATOMIC_RELAXED, __HIP_MEMORY_SCOPE_AGENT);
            const unsigned tgt = (unsigned)(s + 1) * 256u;
            while (__hip_atomic_load(bar, __ATOMIC_RELAXED, __HIP_MEMORY_SCOPE_AGENT) < tgt)
                __builtin_amdgcn_s_sleep(8);
        }
        __syncthreads();
        asm volatile("" ::: "memory");   // no IR motion of h loads above the spin

        // ========== Phase B: h.W part (K=0..511) ==============================
#pragma unroll
        for (int i = 0; i < 4; ++i)
            ra[i] = ld_dev(&hp[(r0 + arow + i) * HH + akk]);
#pragma unroll
        for (int q = 0; q < 8; ++q)
            rb[q] = Wall[((q << 3) | kk8) * G4 + bcol];

        for (int c = 0; c < 8; ++c) {
            __syncthreads();
            *(float4*)&a_t[akk][arow] = make_float4(ra[0], ra[1], ra[2], ra[3]);
#pragma unroll
            for (int q = 0; q < 8; ++q)
                b_t[(q << 3) | kk8][bjj] = rb[q];
            __syncthreads();
            if (c < 7) {
                const int k0 = (c + 1) << 6;
#pragma unroll
                for (int i = 0; i < 4; ++i)
                    ra[i] = ld_dev(&hp[(r0 + arow + i) * HH + k0 + akk]);
#pragma unroll
                for (int q = 0; q < 8; ++q)
                    rb[q] = Wall[(k0 + ((q << 3) | kk8)) * G4 + bcol];
            } else {      // prefetch GEMM2 chunk 0 (c is valid after the barrier)
#pragma unroll
                for (int i = 0; i < 4; ++i)
                    rc[i] = ld_dev(&cp[(r0 + arow + i) * HH + akk]);
                rw[0] = Wd[wkk * HH + m0 + wjj];
                rw[1] = Wd[(32 + wkk) * HH + m0 + wjj];
            }
#pragma unroll 8
            for (int kk = 0; kk < 64; ++kk) {
                const float2 av = *(const float2*)&a_t[kk][rgrp << 1];
                const float2 bv = *(const float2*)&b_t[kk][jp << 1];
                a00 += av.x * bv.x; a01 += av.x * bv.y;
                a10 += av.y * bv.x; a11 += av.y * bv.y;
            }
        }

        // write sigmoid(gates) to LDS (re-partitioned at update)
        *(float2*)&gls[(rgrp << 1) + 0][jp << 1] = make_float2(my_sig(a00), my_sig(a01));
        *(float2*)&gls[(rgrp << 1) + 1][jp << 1] = make_float2(my_sig(a10), my_sig(a11));

        // ========== GEMM2: cs1 = tanh(c @ Wd + bd), [32 x 16], K=512 ==========
        float g0 = bias2;
        for (int c2 = 0; c2 < 8; ++c2) {
            __syncthreads();
            *(float4*)&a_t[akk][arow] = make_float4(rc[0], rc[1], rc[2], rc[3]);
            b2t[wkk][wjj]      = rw[0];
            b2t[32 + wkk][wjj] = rw[1];
            __syncthreads();
            if (c2 < 7) {
                const int k0 = (c2 + 1) << 6;
#pragma unroll
                for (int i = 0; i < 4; ++i)
                    rc[i] = ld_dev(&cp[(r0 + arow + i) * HH + k0 + akk]);
                rw[0] = Wd[(k0 + wkk) * HH + m0 + wjj];
                rw[1] = Wd[(k0 + 32 + wkk) * HH + m0 + wjj];
            }
#pragma unroll 8
            for (int kk = 0; kk < 64; ++kk)
                g0 += a_t[kk][rl] * b2t[kk][mj];
        }
        const float cs1v = my_tanh(g0);

        // ========== state update (all-register except gls reads) ==============
        {
            const float f  = gls[rl][mj];
            const float ii = gls[rl][16 + mj];
            const float oo = gls[rl][32 + mj];
            const float ct = gls[rl][48 + mj];
            const float tv = tsT[s * BB + r0 + rl];
            const float cadj = creg + cs1v * (tv - 1.0f);
            const float cnew = f * cadj + ii * ct;
            const float hnew = oo * my_tanh(cnew);
            creg = cnew; hsreg += hnew;
            const int gidx = (r0 + rl) * HH + m0 + mj;
            st_dev(&cn[gidx], cnew);
            st_dev(&hn[gidx], hnew);
        }
    }

    // ---- hsum output (block tile fully covered, one elem/thread) ----
    hsum[(r0 + rl) * HH + m0 + mj] = hsreg;
}

// Tail: sub = relu(tfidf@fcw+b); x = [sub | hsum/512]; 3-layer MLP. 1 block per row.
__global__ void __launch_bounds__(256)
tail_kernel(const float* __restrict__ tfidf, const float* __restrict__ hsum,
            const float* __restrict__ fcw, const float* __restrict__ fcb,
            const float* __restrict__ l1w, const float* __restrict__ l1b,
            const float* __restrict__ l2w, const float* __restrict__ l2b,
            const float* __restrict__ low, const float* __restrict__ lob,
            float* __restrict__ out)
{
    const int row = blockIdx.x;
    const int t = threadIdx.x;
    __shared__ float tf[800];
    __shared__ float xrow[1024];
    __shared__ float y1[256];
    __shared__ float y2[128];

    for (int k = t; k < NTF; k += 256) tf[k] = tfidf[row * NTF + k];
    __syncthreads();

    for (int n = t; n < 512; n += 256) {
        float acc = fcb[n];
        for (int k = 0; k < NTF; ++k) acc += tf[k] * fcw[k * 512 + n];
        xrow[n] = fmaxf(acc, 0.f);
    }
    for (int n = t; n < 512; n += 256)
        xrow[512 + n] = hsum[row * HH + n] * (1.0f / 512.0f);
    __syncthreads();

    {
        float acc = l1b[t];
        for (int k = 0; k < 1024; ++k) acc += xrow[k] * l1w[k * 256 + t];
        y1[t] = fmaxf(acc, 0.f);
    }
    __syncthreads();
    if (t < 128) {
        float acc = l2b[t];
        for (int k = 0; k < 256; ++k) acc += y1[k] * l2w[k * 128 + t];
        y2[t] = fmaxf(acc, 0.f);
    }
    __syncthreads();
    if (t < 2) {
        float acc = lob[t];
        for (int k = 0; k < 128; ++k) acc += y2[k] * low[k * 2 + t];
        out[row * 2 + t] = acc;
    }
}

extern "C" void kernel_launch(void* const* d_in, const int* in_sizes, int n_in,
                              void* d_out, int out_size, void* d_ws, size_t ws_size,
                              hipStream_t stream)
{
    const float* x     = (const float*)d_in[0];
    const float* ts    = (const float*)d_in[1];
    const float* tfidf = (const float*)d_in[2];
    const float* Wall  = (const float*)d_in[3];
    const float* ball  = (const float*)d_in[4];
    const float* Uall  = (const float*)d_in[5];
    const float* bu    = (const float*)d_in[6];
    const float* Wd    = (const float*)d_in[7];
    const float* bd    = (const float*)d_in[8];
    const float* fcw   = (const float*)d_in[9];
    const float* fcb   = (const float*)d_in[10];
    const float* l1w   = (const float*)d_in[11];
    const float* l1b   = (const float*)d_in[12];
    const float* l2w   = (const float*)d_in[13];
    const float* l2b   = (const float*)d_in[14];
    const float* low   = (const float*)d_in[15];
    const float* lob   = (const float*)d_in[16];
    float* out = (float*)d_out;

    float* ws  = (float*)d_ws;
    float* h0  = ws;
    float* h1  = h0 + BB * HH;
    float* c0  = h1 + BB * HH;
    float* c1  = c0 + BB * HH;
    float* hs  = c1 + BB * HH;
    float* tsT = hs + BB * HH;
    unsigned* bar = (unsigned*)(tsT + BB * SS);

    void* args[] = { (void*)&x, (void*)&ts, (void*)&Wall, (void*)&ball, (void*)&Uall,
                     (void*)&bu, (void*)&Wd, (void*)&bd,
                     (void*)&h0, (void*)&h1, (void*)&c0, (void*)&c1,
                     (void*)&hs, (void*)&tsT, (void*)&bar };
    hipLaunchCooperativeKernel((void*)lstm_persistent, dim3(256), dim3(512), args, 0, stream);

    tail_kernel<<<256, 256, 0, stream>>>(tfidf, hs, fcw, fcb, l1w, l1b, l2w, l2b,
                                         low, lob, out);
}

// Round 8
// 22510.574 us; speedup vs baseline: 5.2572x; 1.2087x over previous
//
#include <hip/hip_runtime.h>
#include <hip/hip_cooperative_groups.h>

namespace cg = cooperative_groups;

#define BB 256
#define SS 512
#define EE 512
#define HH 512
#define G4 2048
#define NTF 799

typedef __attribute__((ext_vector_type(8))) short bf16x8;
typedef __attribute__((ext_vector_type(4))) float f32x4;

__device__ __forceinline__ float my_sig(float v) { return 1.0f / (1.0f + __expf(-v)); }
__device__ __forceinline__ float my_tanh(float v) { float e = __expf(2.0f * v); return 1.0f - 2.0f / (e + 1.0f); }

// Verified (r4-r7) coherence: cross-block h/c via relaxed agent-scope (sc1)
// atomics -> L3-coherent; no cache-inv fences ever -> weights stay L2-hot.
__device__ __forceinline__ float ld_dev(const float* p) {
    return __hip_atomic_load(p, __ATOMIC_RELAXED, __HIP_MEMORY_SCOPE_AGENT);
}
__device__ __forceinline__ void st_dev(float* p, float v) {
    __hip_atomic_store(p, v, __ATOMIC_RELAXED, __HIP_MEMORY_SCOPE_AGENT);
}

__device__ __forceinline__ unsigned short f2bf(float f) {   // RNE fp32->bf16
    unsigned u = __builtin_bit_cast(unsigned, f);
    u = (u + 0x7FFFu + ((u >> 16) & 1u)) >> 16;
    return (unsigned short)u;
}
__device__ __forceinline__ float bf2f(unsigned short h) {
    unsigned u = ((unsigned)h) << 16;
    return __builtin_bit_cast(float, u);
}

// ---------------------------------------------------------------------------
// Prep: split Wall/Uall/Wd into bf16 hi/lo pairs laid out in MFMA B-fragment
// order: frag(cgi, kc, wc, term) lane l holds B[k=kc*32+(l>>4)*8+j][col] for
// col = wc*512 + cgi*16 + (l&15)  (kc<16 -> Wall k=kc*32; kc>=16 -> Uall).
// ---------------------------------------------------------------------------
__global__ void __launch_bounds__(256)
prep_split(const float* __restrict__ Wall, const float* __restrict__ Uall,
           const float* __restrict__ Wd,
           unsigned short* __restrict__ B1, unsigned short* __restrict__ B2)
{
    const int t = blockIdx.x * 256 + threadIdx.x;
    if (t < 262144) {
        const int lane = t & 63, wc = (t >> 6) & 3, kc = (t >> 8) & 31, cgi = t >> 13;
        const int kb = ((kc & 15) << 5) + ((lane >> 4) << 3);
        const int col = (wc << 9) + (cgi << 4) + (lane & 15);
        const float* src = (kc < 16) ? Wall : Uall;
        bf16x8 vh, vl;
#pragma unroll
        for (int j = 0; j < 8; ++j) {
            float f = src[(size_t)(kb + j) * G4 + col];
            unsigned short h16 = f2bf(f);
            vh[j] = (short)h16;
            vl[j] = (short)f2bf(f - bf2f(h16));
        }
        const int g = t >> 6;
        *(bf16x8*)(B1 + ((size_t)(g * 2 + 0) * 64 + lane) * 8) = vh;
        *(bf16x8*)(B1 + ((size_t)(g * 2 + 1) * 64 + lane) * 8) = vl;
    } else if (t < 262144 + 32768) {
        const int u = t - 262144;
        const int lane = u & 63, kch = (u >> 6) & 15, cgi = u >> 10;
        const int kb = (kch << 5) + ((lane >> 4) << 3);
        const int col = (cgi << 4) + (lane & 15);
        bf16x8 vh, vl;
#pragma unroll
        for (int j = 0; j < 8; ++j) {
            float f = Wd[(size_t)(kb + j) * HH + col];
            unsigned short h16 = f2bf(f);
            vh[j] = (short)h16;
            vl[j] = (short)f2bf(f - bf2f(h16));
        }
        const int g = u >> 6;
        *(bf16x8*)(B2 + ((size_t)(g * 2 + 0) * 64 + lane) * 8) = vh;
        *(bf16x8*)(B2 + ((size_t)(g * 2 + 1) * 64 + lane) * 8) = vl;
    }
}

// staging regs -> LDS as split bf16, 16B-chunk XOR swizzle (2-way = free)
#define STAGE_WRITE(bufi)                                                     \
    { bf16x8 vh, vl;                                                          \
      _Pragma("unroll")                                                       \
      for (int j = 0; j < 8; ++j) {                                           \
          unsigned short h16 = f2bf(rs[j]);                                   \
          vh[j] = (short)h16;                                                 \
          vl[j] = (short)f2bf(rs[j] - bf2f(h16));                             \
      }                                                                       \
      const int slot_ = (scid ^ (srow & 7)) << 3;                             \
      *(bf16x8*)&Ahi[bufi][srow][slot_] = vh;                                 \
      *(bf16x8*)&Alo[bufi][srow][slot_] = vl; }

#define XLOAD(dst, sidx, p)                                                   \
    { const float* xp_ = x + (size_t)(r0 + srow) * (SS * EE)                  \
                           + (size_t)(sidx) * EE + (p) * 128 + scid * 8;      \
      float4 v0_ = *(const float4*)xp_;                                       \
      float4 v1_ = *(const float4*)(xp_ + 4);                                 \
      dst[0]=v0_.x; dst[1]=v0_.y; dst[2]=v0_.z; dst[3]=v0_.w;                 \
      dst[4]=v1_.x; dst[5]=v1_.y; dst[6]=v1_.z; dst[7]=v1_.w; }

#define HLOAD(dst, base, p)                                                   \
    { _Pragma("unroll")                                                       \
      for (int j = 0; j < 8; ++j)                                             \
          dst[j] = ld_dev((base) + (r0 + srow) * HH + (p) * 128 + scid * 8 + j); }

#define B1FRAG(kcv, term) (*(const bf16x8*)(B1 +                              \
    ((size_t)(((cgi * 32 + (kcv)) * 4 + wc) * 2 + (term)) * 64 + lane) * 8))
#define B2FRAG(kchv, term) (*(const bf16x8*)(B2 +                             \
    ((size_t)((cgi * 16 + (kchv)) * 2 + (term)) * 64 + lane) * 8))

// 4 K-steps x split-3 MFMA from LDS A-frags + register B-frags
#define MFMA3(accv, arowv)                                                    \
    { const int arow_ = (arowv);                                              \
      _Pragma("unroll")                                                       \
      for (int q = 0; q < 4; ++q) {                                           \
          const int slot_ = ((((q << 2) + lk8) ^ (arow_ & 7)) << 3);          \
          bf16x8 ah_ = *(const bf16x8*)&Ahi[buf][arow_][slot_];               \
          bf16x8 al_ = *(const bf16x8*)&Alo[buf][arow_][slot_];               \
          accv = __builtin_amdgcn_mfma_f32_16x16x32_bf16(ah_, bh[q], accv, 0, 0, 0); \
          accv = __builtin_amdgcn_mfma_f32_16x16x32_bf16(ah_, bl[q], accv, 0, 0, 0); \
          accv = __builtin_amdgcn_mfma_f32_16x16x32_bf16(al_, bh[q], accv, 0, 0, 0); \
      } }

// ---------------------------------------------------------------------------
// Persistent time-LSTM, MFMA bf16-split-3. 256 blocks x 512 threads.
// Tile: 32 rows x 16 h-cols (64 gate cols) = 8 waves x one 16x16 MFMA tile.
// Step: [4 x.U phases | barrier | 4 h.W phases | 4 c.Wd phases | update].
// ---------------------------------------------------------------------------
__global__ void __launch_bounds__(512)
lstm_persistent(const float* __restrict__ x, const float* __restrict__ ts,
                const float* __restrict__ ball, const float* __restrict__ bu,
                const float* __restrict__ bd,
                const unsigned short* __restrict__ B1,
                const unsigned short* __restrict__ B2,
                float* __restrict__ h0, float* __restrict__ h1,
                float* __restrict__ c0, float* __restrict__ c1,
                float* __restrict__ hsum, float* __restrict__ tsT,
                unsigned* __restrict__ bar)
{
    cg::grid_group grid = cg::this_grid();
    const int tid = threadIdx.x;
    const int bid = blockIdx.x;
    const int gtid = (bid << 9) + tid;

    for (int i = gtid; i < BB * HH; i += 131072) { h0[i] = 0.f; c0[i] = 0.f; }
    for (int i = gtid; i < BB * SS; i += 131072) {
        int b = i >> 9, s = i & 511;
        tsT[s * BB + b] = ts[i];
    }
    if (gtid == 0) *bar = 0u;
    grid.sync();

    // XCD-aware bijective relabeling (perf heuristic only)
    const int xcd = bid & 7, tt = bid >> 3;
    const int cgi = (xcd << 2) | (tt & 3);   // 0..31
    const int rg  = tt >> 2;                 // 0..7
    const int r0  = rg << 5;                 // 32 rows
    const int m0  = cgi << 4;                // 16 h-cols -> 64 gate cols

    const int wid = tid >> 6, lane = tid & 63;
    const int wr = wid >> 2, wc = wid & 3;     // 2x4 wave grid of 16x16 tiles
    const int lrow = lane & 15, lk8 = lane >> 4;
    const int srow = tid >> 4, scid = tid & 15; // staging: row, 16B chunk
    const int rl = srow, mj = scid;             // update mapping (identity)

    __shared__ __align__(16) unsigned short Ahi[2][32][128];
    __shared__ __align__(16) unsigned short Alo[2][32][128];
    __shared__ __align__(16) float gls[32][68];
    __shared__ __align__(16) float csl[32][20];

    const float biasg  = ball[(wc << 9) + m0 + lrow] + bu[(wc << 9) + m0 + lrow];
    const float bias2v = bd[m0 + lrow];

    float creg = 0.f, hsreg = 0.f;
    float rs[8];
    bf16x8 bh[4], bl[4];

    // prologue: x(s=0, phase0) + B1 frags kc 16..19 (x.U part)
    XLOAD(rs, 0, 0);
#pragma unroll
    for (int q = 0; q < 4; ++q) { bh[q] = B1FRAG(16 + q, 0); bl[q] = B1FRAG(16 + q, 1); }

    int buf = 0;
#pragma unroll 1
    for (int s = 0; s < SS; ++s) {
        const float* hp = (s & 1) ? h1 : h0;
        const float* cp = (s & 1) ? c1 : c0;
        float* hn = (s & 1) ? h0 : h1;
        float* cn = (s & 1) ? c0 : c1;
        const int sn = (s < SS - 1) ? s + 1 : s;

        f32x4 acc = {biasg, biasg, biasg, biasg};

        // ================= 4 x.U phases (kc 16..31) =================
#pragma unroll
        for (int p = 0; p < 4; ++p) {
            __syncthreads();
            STAGE_WRITE(buf);
            __syncthreads();
            float nrs[8]; bf16x8 nbh[4], nbl[4];
            if (p < 3) {
                XLOAD(nrs, s, p + 1);
#pragma unroll
                for (int q = 0; q < 4; ++q) { nbh[q] = B1FRAG(20 + p * 4 + q, 0); nbl[q] = B1FRAG(20 + p * 4 + q, 1); }
            } else {
#pragma unroll
                for (int q = 0; q < 4; ++q) { nbh[q] = B1FRAG(q, 0); nbl[q] = B1FRAG(q, 1); }
#pragma unroll
                for (int j = 0; j < 8; ++j) nrs[j] = 0.f;
            }
            MFMA3(acc, (wr << 4) + lrow);
#pragma unroll
            for (int q = 0; q < 4; ++q) { bh[q] = nbh[q]; bl[q] = nbl[q]; }
#pragma unroll
            for (int j = 0; j < 8; ++j) rs[j] = nrs[j];
            buf ^= 1;
        }

        // ============== global barrier (h/c of step s now visible) ==========
        asm volatile("s_waitcnt vmcnt(0)" ::: "memory");
        __syncthreads();
        if (tid == 0) {
            __hip_atomic_fetch_add(bar, 1u, __ATOMIC_RELAXED, __HIP_MEMORY_SCOPE_AGENT);
            const unsigned tgt = (unsigned)(s + 1) * 256u;
            while (__hip_atomic_load(bar, __ATOMIC_RELAXED, __HIP_MEMORY_SCOPE_AGENT) < tgt)
                __builtin_amdgcn_s_sleep(8);
        }
        __syncthreads();
        asm volatile("" ::: "memory");

        HLOAD(rs, hp, 0);

        // ================= 4 h.W phases (kc 0..15) =================
#pragma unroll
        for (int p = 0; p < 4; ++p) {
            __syncthreads();
            STAGE_WRITE(buf);
            __syncthreads();
            float nrs[8]; bf16x8 nbh[4], nbl[4];
            if (p < 3) {
                HLOAD(nrs, hp, p + 1);
#pragma unroll
                for (int q = 0; q < 4; ++q) { nbh[q] = B1FRAG(p * 4 + 4 + q, 0); nbl[q] = B1FRAG(p * 4 + 4 + q, 1); }
            } else {
                HLOAD(nrs, cp, 0);
#pragma unroll
                for (int q = 0; q < 4; ++q) { nbh[q] = B2FRAG(q, 0); nbl[q] = B2FRAG(q, 1); }
            }
            MFMA3(acc, (wr << 4) + lrow);
#pragma unroll
            for (int q = 0; q < 4; ++q) { bh[q] = nbh[q]; bl[q] = nbl[q]; }
#pragma unroll
            for (int j = 0; j < 8; ++j) rs[j] = nrs[j];
            buf ^= 1;
        }

        // gates -> LDS (D layout: col=lane&15, row=(lane>>4)*4+reg)
#pragma unroll
        for (int i = 0; i < 4; ++i)
            gls[(wr << 4) + (lk8 << 2) + i][(wc << 4) + lrow] = my_sig(acc[i]);

        f32x4 acc2 = {bias2v, bias2v, bias2v, bias2v};

        // ================= 4 c.Wd phases (GEMM2, waves 0,1 compute) =========
#pragma unroll
        for (int p = 0; p < 4; ++p) {
            __syncthreads();
            STAGE_WRITE(buf);
            __syncthreads();
            float nrs[8]; bf16x8 nbh[4], nbl[4];
            if (p < 3) {
                HLOAD(nrs, cp, p + 1);
#pragma unroll
                for (int q = 0; q < 4; ++q) { nbh[q] = B2FRAG(p * 4 + 4 + q, 0); nbl[q] = B2FRAG(p * 4 + 4 + q, 1); }
            } else {
                XLOAD(nrs, sn, 0);
#pragma unroll
                for (int q = 0; q < 4; ++q) { nbh[q] = B1FRAG(16 + q, 0); nbl[q] = B1FRAG(16 + q, 1); }
            }
            if (wid < 2) { MFMA3(acc2, ((wid & 1) << 4) + lrow); }
#pragma unroll
            for (int q = 0; q < 4; ++q) { bh[q] = nbh[q]; bl[q] = nbl[q]; }
#pragma unroll
            for (int j = 0; j < 8; ++j) rs[j] = nrs[j];
            buf ^= 1;
        }

        if (wid < 2) {
#pragma unroll
            for (int i = 0; i < 4; ++i)
                csl[(wid << 4) + (lk8 << 2) + i][lrow] = my_tanh(acc2[i]);
        }
        __syncthreads();

        // ================= state update (1 elem/thread) =================
        {
            const float f  = gls[rl][mj];
            const float ii = gls[rl][16 + mj];
            const float oo = gls[rl][32 + mj];
            const float ct = gls[rl][48 + mj];
            const float cs1v = csl[rl][mj];
            const float tv = tsT[s * BB + r0 + rl];
            const float cadj = creg + cs1v * (tv - 1.0f);
            const float cnew = f * cadj + ii * ct;
            const float hnew = oo * my_tanh(cnew);
            creg = cnew; hsreg += hnew;
            const int gidx = (r0 + rl) * HH + m0 + mj;
            st_dev(&cn[gidx], cnew);
            st_dev(&hn[gidx], hnew);
        }
    }

    hsum[(r0 + rl) * HH + m0 + mj] = hsreg;
}

// Tail: sub = relu(tfidf@fcw+b); x = [sub | hsum/512]; 3-layer MLP (fp32).
__global__ void __launch_bounds__(256)
tail_kernel(const float* __restrict__ tfidf, const float* __restrict__ hsum,
            const float* __restrict__ fcw, const float* __restrict__ fcb,
            const float* __restrict__ l1w, const float* __restrict__ l1b,
            const float* __restrict__ l2w, const float* __restrict__ l2b,
            const float* __restrict__ low, const float* __restrict__ lob,
            float* __restrict__ out)
{
    const int row = blockIdx.x;
    const int t = threadIdx.x;
    __shared__ float tf[800];
    __shared__ float xrow[1024];
    __shared__ float y1[256];
    __shared__ float y2[128];

    for (int k = t; k < NTF; k += 256) tf[k] = tfidf[row * NTF + k];
    __syncthreads();

    for (int n = t; n < 512; n += 256) {
        float acc = fcb[n];
        for (int k = 0; k < NTF; ++k) acc += tf[k] * fcw[k * 512 + n];
        xrow[n] = fmaxf(acc, 0.f);
    }
    for (int n = t; n < 512; n += 256)
        xrow[512 + n] = hsum[row * HH + n] * (1.0f / 512.0f);
    __syncthreads();

    {
        float acc = l1b[t];
        for (int k = 0; k < 1024; ++k) acc += xrow[k] * l1w[k * 256 + t];
        y1[t] = fmaxf(acc, 0.f);
    }
    __syncthreads();
    if (t < 128) {
        float acc = l2b[t];
        for (int k = 0; k < 256; ++k) acc += y1[k] * l2w[k * 128 + t];
        y2[t] = fmaxf(acc, 0.f);
    }
    __syncthreads();
    if (t < 2) {
        float acc = lob[t];
        for (int k = 0; k < 128; ++k) acc += y2[k] * low[k * 2 + t];
        out[row * 2 + t] = acc;
    }
}

extern "C" void kernel_launch(void* const* d_in, const int* in_sizes, int n_in,
                              void* d_out, int out_size, void* d_ws, size_t ws_size,
                              hipStream_t stream)
{
    const float* x     = (const float*)d_in[0];
    const float* ts    = (const float*)d_in[1];
    const float* tfidf = (const float*)d_in[2];
    const float* Wall  = (const float*)d_in[3];
    const float* ball  = (const float*)d_in[4];
    const float* Uall  = (const float*)d_in[5];
    const float* bu    = (const float*)d_in[6];
    const float* Wd    = (const float*)d_in[7];
    const float* bd    = (const float*)d_in[8];
    const float* fcw   = (const float*)d_in[9];
    const float* fcb   = (const float*)d_in[10];
    const float* l1w   = (const float*)d_in[11];
    const float* l1b   = (const float*)d_in[12];
    const float* l2w   = (const float*)d_in[13];
    const float* l2b   = (const float*)d_in[14];
    const float* low   = (const float*)d_in[15];
    const float* lob   = (const float*)d_in[16];
    float* out = (float*)d_out;

    float* ws  = (float*)d_ws;
    float* h0  = ws;
    float* h1  = h0 + BB * HH;
    float* c0  = h1 + BB * HH;
    float* c1  = c0 + BB * HH;
    float* hs  = c1 + BB * HH;
    float* tsT = hs + BB * HH;
    unsigned* bar = (unsigned*)(tsT + BB * SS);
    unsigned short* B1 = (unsigned short*)(bar + 64);          // 16B-aligned
    unsigned short* B2 = B1 + (size_t)32 * 32 * 4 * 2 * 64 * 8; // B1 = 8MB

    prep_split<<<1152, 256, 0, stream>>>(Wall, Uall, Wd, B1, B2);

    void* args[] = { (void*)&x, (void*)&ts, (void*)&ball, (void*)&bu, (void*)&bd,
                     (void*)&B1, (void*)&B2,
                     (void*)&h0, (void*)&h1, (void*)&c0, (void*)&c1,
                     (void*)&hs, (void*)&tsT, (void*)&bar };
    hipLaunchCooperativeKernel((void*)lstm_persistent, dim3(256), dim3(512), args, 0, stream);

    tail_kernel<<<256, 256, 0, stream>>>(tfidf, hs, fcw, fcb, l1w, l1b, l2w, l2b,
                                         low, lob, out);
}

// Round 9
// 11926.963 us; speedup vs baseline: 9.9222x; 1.8874x over previous
//
#include <hip/hip_runtime.h>
#include <hip/hip_cooperative_groups.h>

namespace cg = cooperative_groups;

#define BB 256
#define SS 512
#define EE 512
#define HH 512
#define G4 2048
#define NTF 799

typedef __attribute__((ext_vector_type(8))) short bf16x8;
typedef __attribute__((ext_vector_type(4))) float f32x4;

__device__ __forceinline__ float my_sig(float v) { return 1.0f / (1.0f + __expf(-v)); }
__device__ __forceinline__ float my_tanh(float v) { float e = __expf(2.0f * v); return 1.0f - 2.0f / (e + 1.0f); }

__device__ __forceinline__ unsigned short f2bf(float f) {   // RNE fp32->bf16
    unsigned u = __builtin_bit_cast(unsigned, f);
    u = (u + 0x7FFFu + ((u >> 16) & 1u)) >> 16;
    return (unsigned short)u;
}
__device__ __forceinline__ float bf2f(unsigned short h) {
    unsigned u = ((unsigned)h) << 16;
    return __builtin_bit_cast(float, u);
}
// pack f32 -> (hi_bf16 << 16) | lo_bf16   (split-3 operand pair in one u32)
__device__ __forceinline__ unsigned packsplit(float f) {
    unsigned short hi = f2bf(f);
    unsigned short lo = f2bf(f - bf2f(hi));
    return ((unsigned)hi << 16) | (unsigned)lo;
}
// unpack 8 packed u32 (two uint4) -> hi / lo bf16x8 fragments
__device__ __forceinline__ bf16x8 unhi(uint4 a, uint4 b) {
    union { unsigned u[4]; bf16x8 v; } r;
    r.u[0] = __builtin_amdgcn_perm(a.y, a.x, 0x07060302u);
    r.u[1] = __builtin_amdgcn_perm(a.w, a.z, 0x07060302u);
    r.u[2] = __builtin_amdgcn_perm(b.y, b.x, 0x07060302u);
    r.u[3] = __builtin_amdgcn_perm(b.w, b.z, 0x07060302u);
    return r.v;
}
__device__ __forceinline__ bf16x8 unlo(uint4 a, uint4 b) {
    union { unsigned u[4]; bf16x8 v; } r;
    r.u[0] = __builtin_amdgcn_perm(a.y, a.x, 0x05040100u);
    r.u[1] = __builtin_amdgcn_perm(a.w, a.z, 0x05040100u);
    r.u[2] = __builtin_amdgcn_perm(b.y, b.x, 0x05040100u);
    r.u[3] = __builtin_amdgcn_perm(b.w, b.z, 0x05040100u);
    return r.v;
}

// sc1 coherent accesses (verified r4-r8): bypass stale L2, coherent at L3
__device__ __forceinline__ void ld4_sc1(uint4& d, const unsigned* p) {
    asm volatile("global_load_dwordx4 %0, %1, off sc0 sc1" : "=v"(d) : "v"(p));
}
__device__ __forceinline__ void st_devu(unsigned* p, unsigned v) {
    __hip_atomic_store(p, v, __ATOMIC_RELAXED, __HIP_MEMORY_SCOPE_AGENT);
}

// ---------------------------------------------------------------------------
// Prep (verbatim from r8, verified): split weights into bf16 hi/lo MFMA
// B-fragments. B1: frag(cgi,kc,wc,term); kc<16 -> Wall k=kc*32, else Uall.
// ---------------------------------------------------------------------------
__global__ void __launch_bounds__(256)
prep_split(const float* __restrict__ Wall, const float* __restrict__ Uall,
           const float* __restrict__ Wd,
           unsigned short* __restrict__ B1, unsigned short* __restrict__ B2)
{
    const int t = blockIdx.x * 256 + threadIdx.x;
    if (t < 262144) {
        const int lane = t & 63, wc = (t >> 6) & 3, kc = (t >> 8) & 31, cgi = t >> 13;
        const int kb = ((kc & 15) << 5) + ((lane >> 4) << 3);
        const int col = (wc << 9) + (cgi << 4) + (lane & 15);
        const float* src = (kc < 16) ? Wall : Uall;
        bf16x8 vh, vl;
#pragma unroll
        for (int j = 0; j < 8; ++j) {
            float f = src[(size_t)(kb + j) * G4 + col];
            unsigned short h16 = f2bf(f);
            vh[j] = (short)h16;
            vl[j] = (short)f2bf(f - bf2f(h16));
        }
        const int g = t >> 6;
        *(bf16x8*)(B1 + ((size_t)(g * 2 + 0) * 64 + lane) * 8) = vh;
        *(bf16x8*)(B1 + ((size_t)(g * 2 + 1) * 64 + lane) * 8) = vl;
    } else if (t < 262144 + 32768) {
        const int u = t - 262144;
        const int lane = u & 63, kch = (u >> 6) & 15, cgi = u >> 10;
        const int kb = (kch << 5) + ((lane >> 4) << 3);
        const int col = (cgi << 4) + (lane & 15);
        bf16x8 vh, vl;
#pragma unroll
        for (int j = 0; j < 8; ++j) {
            float f = Wd[(size_t)(kb + j) * HH + col];
            unsigned short h16 = f2bf(f);
            vh[j] = (short)h16;
            vl[j] = (short)f2bf(f - bf2f(h16));
        }
        const int g = u >> 6;
        *(bf16x8*)(B2 + ((size_t)(g * 2 + 0) * 64 + lane) * 8) = vh;
        *(bf16x8*)(B2 + ((size_t)(g * 2 + 1) * 64 + lane) * 8) = vl;
    }
}

#define B1FRAG(kcv, wcv, term) (*(const bf16x8*)(B1 +                          \
    ((size_t)(((cgi * 32 + (kcv)) * 4 + (wcv)) * 2 + (term)) * 64 + lane) * 8))
#define B2FRAG(kchv, term) (*(const bf16x8*)(B2 +                              \
    ((size_t)((cgi * 16 + (kchv)) * 2 + (term)) * 64 + lane) * 8))

// ---------------------------------------------------------------------------
// Persistent time-LSTM. 256 blocks x 512 threads (8 waves). Block tile:
// 32 rows x 16 h-cols (64 gate cols). K-SPLIT across waves: wave w holds its
// 32 B1-frags + 4 B2-frags in REGISTERS for all 512 steps (weights never
// re-fetched). h/c stored packed (hi|lo bf16 in u32). Per step:
//   [stage x | x-partial MFMAs (waves 4-7)] | grid barrier |
//   [stage h | h-partial MFMAs (waves 0-3) + partial writes | stage c |
//    gate-reduce + cs1 MFMAs | cs1-reduce + update]
// ---------------------------------------------------------------------------
__global__ void __launch_bounds__(512, 2)
lstm_persistent(const float* __restrict__ x, const float* __restrict__ ts,
                const float* __restrict__ ball, const float* __restrict__ bu,
                const float* __restrict__ bd,
                const unsigned short* __restrict__ B1,
                const unsigned short* __restrict__ B2,
                unsigned* __restrict__ h2a, unsigned* __restrict__ h2b,
                unsigned* __restrict__ c2a, unsigned* __restrict__ c2b,
                float* __restrict__ hsum, float* __restrict__ tsT,
                unsigned* __restrict__ bar)
{
    cg::grid_group grid = cg::this_grid();
    const int tid = threadIdx.x;
    const int bid = blockIdx.x;
    const int gtid = (bid << 9) + tid;

    for (int i = gtid; i < BB * HH; i += 131072) { h2a[i] = 0u; c2a[i] = 0u; }
    for (int i = gtid; i < BB * SS; i += 131072) {
        int b = i >> 9, s = i & 511;
        tsT[s * BB + b] = ts[i];
    }
    if (gtid == 0) *bar = 0u;
    grid.sync();

    // XCD-aware bijective relabeling (perf heuristic only)
    const int xcd = bid & 7, tt = bid >> 3;
    const int cgi = (xcd << 2) | (tt & 3);   // 0..31 -> m0
    const int rg  = tt >> 2;                 // 0..7  -> r0
    const int r0  = rg << 5;
    const int m0  = cgi << 4;

    const int wid = tid >> 6, lane = tid & 63;
    const int lrow = lane & 15, lk8 = lane >> 4;
    const int wq  = wid & 3;                 // K-window within region
    const int srow = tid >> 4, scb = tid & 15;  // staging row / chunk base
    const int rl = srow, mj = scb;              // reduce+update mapping

    // two 64KB LDS regions, packed-u32 A tiles [32 rows][512 K], 16B chunks
    // swizzled  chunk^ (row&7)
    __shared__ __align__(16) unsigned R1[32 * 512];  // AX -> gate partials -> cs1 partials
    __shared__ __align__(16) unsigned R2[32 * 512];  // AH -> AC
    uint4* R1v = (uint4*)R1;
    uint4* R2v = (uint4*)R2;
    float* gp  = (float*)R1;   // gate partials [32][8][64]
    float* gp2 = (float*)R1;   // cs1 partials  [32][8][16]

    // ---- register-resident weight fragments ----
    bf16x8 b1h[4][4], b1l[4][4], b2h[2], b2l[2];
    const int kcb = (wid < 4) ? (wid << 2) : (16 + ((wid - 4) << 2));
#pragma unroll
    for (int q = 0; q < 4; ++q)
#pragma unroll
        for (int wc = 0; wc < 4; ++wc) {
            b1h[q][wc] = B1FRAG(kcb + q, wc, 0);
            b1l[q][wc] = B1FRAG(kcb + q, wc, 1);
        }
#pragma unroll
    for (int kq = 0; kq < 2; ++kq) {
        b2h[kq] = B2FRAG((wid << 1) + kq, 0);
        b2l[kq] = B2FRAG((wid << 1) + kq, 1);
    }

    float bias4[4];
#pragma unroll
    for (int k = 0; k < 4; ++k)
        bias4[k] = ball[(k << 9) + m0 + mj] + bu[(k << 9) + m0 + mj];
    const float bias2v = bd[m0 + mj];

    float creg = 0.f, hsreg = 0.f;

    // GEMM1 partial MFMAs over one region (wave K-window wq*128..+128)
#define DO_G1(Rv)                                                              \
    _Pragma("unroll")                                                          \
    for (int q = 0; q < 4; ++q) {                                              \
        _Pragma("unroll")                                                      \
        for (int wr = 0; wr < 2; ++wr) {                                       \
            const int row_ = (wr << 4) | lrow;                                 \
            const int cb_  = (((wq << 2) + q) << 3) + (lk8 << 1);              \
            uint4 qa = Rv[row_ * 128 + (cb_ ^ (row_ & 7))];                    \
            uint4 qb = Rv[row_ * 128 + ((cb_ + 1) ^ (row_ & 7))];              \
            bf16x8 ah = unhi(qa, qb), al = unlo(qa, qb);                       \
            _Pragma("unroll")                                                  \
            for (int wc = 0; wc < 4; ++wc) {                                   \
                acc[wr][wc] = __builtin_amdgcn_mfma_f32_16x16x32_bf16(ah, b1h[q][wc], acc[wr][wc], 0, 0, 0); \
                acc[wr][wc] = __builtin_amdgcn_mfma_f32_16x16x32_bf16(ah, b1l[q][wc], acc[wr][wc], 0, 0, 0); \
                acc[wr][wc] = __builtin_amdgcn_mfma_f32_16x16x32_bf16(al, b1h[q][wc], acc[wr][wc], 0, 0, 0); \
            }                                                                  \
        }                                                                      \
    }

#pragma unroll 1
    for (int s = 0; s < SS; ++s) {
        const unsigned* h2p = (s & 1) ? h2b : h2a;
        const unsigned* c2p = (s & 1) ? c2b : c2a;
        unsigned* h2n = (s & 1) ? h2a : h2b;
        unsigned* c2n = (s & 1) ? c2a : c2b;

        f32x4 acc[2][4];

        // ---- phase 0: stage AX <- x(s) (pack fp32 -> hi|lo u32) ----
        __syncthreads();                       // R1 free (cs1 reads done)
        {
            const float* xp = x + (size_t)(r0 + srow) * (SS * EE) + (size_t)s * EE;
#pragma unroll
            for (int j = 0; j < 8; ++j) {
                const int ci = scb + (j << 4);
                float4 v = *(const float4*)(xp + (ci << 2));
                uint4 pk;
                pk.x = packsplit(v.x); pk.y = packsplit(v.y);
                pk.z = packsplit(v.z); pk.w = packsplit(v.w);
                R1v[srow * 128 + (ci ^ (srow & 7))] = pk;
            }
        }
        __syncthreads();

        // ---- x-partial MFMAs (waves 4..7), hides barrier wait ----
        if (wid >= 4) {
#pragma unroll
            for (int wr = 0; wr < 2; ++wr)
#pragma unroll
                for (int wc = 0; wc < 4; ++wc) acc[wr][wc] = (f32x4){0.f, 0.f, 0.f, 0.f};
            DO_G1(R1v);
        }

        // ---- grid barrier (h/c of step s visible; r8-verified protocol) ----
        asm volatile("s_waitcnt vmcnt(0)" ::: "memory");
        __syncthreads();
        if (tid == 0) {
            __hip_atomic_fetch_add(bar, 1u, __ATOMIC_RELAXED, __HIP_MEMORY_SCOPE_AGENT);
            const unsigned tgt = (unsigned)(s + 1) * 256u;
            while (__hip_atomic_load(bar, __ATOMIC_RELAXED, __HIP_MEMORY_SCOPE_AGENT) < tgt)
                __builtin_amdgcn_s_sleep(8);
        }
        __syncthreads();
        asm volatile("" ::: "memory");

        // ---- stage AH <- packed h(s): pure sc1 copy ----
        {
            const unsigned* hp = h2p + (r0 + srow) * HH;
            uint4 hv[8];
#pragma unroll
            for (int j = 0; j < 8; ++j) {
                const int ci = scb + (j << 4);
                ld4_sc1(hv[j], hp + (ci << 2));
            }
            asm volatile("s_waitcnt vmcnt(0)" ::: "memory");
            __builtin_amdgcn_sched_barrier(0);
#pragma unroll
            for (int j = 0; j < 8; ++j) {
                const int ci = scb + (j << 4);
                R2v[srow * 128 + (ci ^ (srow & 7))] = hv[j];
            }
        }
        __syncthreads();

        // ---- h-partial MFMAs (waves 0..3) | gate-partial writes (4..7) ----
        if (wid < 4) {
#pragma unroll
            for (int wr = 0; wr < 2; ++wr)
#pragma unroll
                for (int wc = 0; wc < 4; ++wc) acc[wr][wc] = (f32x4){0.f, 0.f, 0.f, 0.f};
            DO_G1(R2v);
        } else {
#pragma unroll
            for (int wr = 0; wr < 2; ++wr)
#pragma unroll
                for (int wc = 0; wc < 4; ++wc)
#pragma unroll
                    for (int i = 0; i < 4; ++i)
                        gp[((wr << 4) + (lk8 << 2) + i) * 512 + (wid << 6) + (wc << 4) + lrow] = acc[wr][wc][i];
        }
        __syncthreads();

        // ---- gate-partial writes (0..3) | stage AC <- packed c(s) (4..7) ----
        if (wid < 4) {
#pragma unroll
            for (int wr = 0; wr < 2; ++wr)
#pragma unroll
                for (int wc = 0; wc < 4; ++wc)
#pragma unroll
                    for (int i = 0; i < 4; ++i)
                        gp[((wr << 4) + (lk8 << 2) + i) * 512 + (wid << 6) + (wc << 4) + lrow] = acc[wr][wc][i];
        } else {
            const int ttc = tid - 256;                // 0..255
            const int crow = ttc >> 3, ccb = ttc & 7;
            const unsigned* cpp = c2p + (r0 + crow) * HH;
#pragma unroll
            for (int g2 = 0; g2 < 2; ++g2) {
                uint4 cv[8];
#pragma unroll
                for (int j = 0; j < 8; ++j) {
                    const int ci = ccb + (((g2 << 3) + j) << 3);
                    ld4_sc1(cv[j], cpp + (ci << 2));
                }
                asm volatile("s_waitcnt vmcnt(0)" ::: "memory");
                __builtin_amdgcn_sched_barrier(0);
#pragma unroll
                for (int j = 0; j < 8; ++j) {
                    const int ci = ccb + (((g2 << 3) + j) << 3);
                    R2v[crow * 128 + (ci ^ (crow & 7))] = cv[j];
                }
            }
        }
        __syncthreads();

        // ---- gate reduce (regs) + GEMM2 partial MFMAs (all waves) ----
        f32x4 acc2[2];
        acc2[0] = (f32x4){0.f, 0.f, 0.f, 0.f};
        acc2[1] = (f32x4){0.f, 0.f, 0.f, 0.f};
#pragma unroll
        for (int kq = 0; kq < 2; ++kq)
#pragma unroll
            for (int wr = 0; wr < 2; ++wr) {
                const int row_ = (wr << 4) | lrow;
                const int cb_  = (((wid << 1) + kq) << 3) + (lk8 << 1);
                uint4 qa = R2v[row_ * 128 + (cb_ ^ (row_ & 7))];
                uint4 qb = R2v[row_ * 128 + ((cb_ + 1) ^ (row_ & 7))];
                bf16x8 ah = unhi(qa, qb), al = unlo(qa, qb);
                acc2[wr] = __builtin_amdgcn_mfma_f32_16x16x32_bf16(ah, b2h[kq], acc2[wr], 0, 0, 0);
                acc2[wr] = __builtin_amdgcn_mfma_f32_16x16x32_bf16(ah, b2l[kq], acc2[wr], 0, 0, 0);
                acc2[wr] = __builtin_amdgcn_mfma_f32_16x16x32_bf16(al, b2h[kq], acc2[wr], 0, 0, 0);
            }
        float gv[4];
#pragma unroll
        for (int k = 0; k < 4; ++k) {
            float sacc = bias4[k];
#pragma unroll
            for (int p = 0; p < 8; ++p)
                sacc += gp[rl * 512 + (p << 6) + (k << 4) + mj];
            gv[k] = my_sig(sacc);
        }
        __syncthreads();

        // ---- cs1 partial writes ----
#pragma unroll
        for (int wr = 0; wr < 2; ++wr)
#pragma unroll
            for (int i = 0; i < 4; ++i)
                gp2[((wr << 4) + (lk8 << 2) + i) * 128 + (wid << 4) + lrow] = acc2[wr][i];
        __syncthreads();

        // ---- cs1 reduce + state update (all in regs) ----
        {
            float sacc = bias2v;
#pragma unroll
            for (int p = 0; p < 8; ++p)
                sacc += gp2[rl * 128 + (p << 4) + mj];
            const float cs1v = my_tanh(sacc);
            const float tv = tsT[s * BB + r0 + rl];
            const float cadj = creg + cs1v * (tv - 1.0f);
            const float cnew = gv[0] * cadj + gv[1] * gv[3];
            const float hnew = gv[2] * my_tanh(cnew);
            creg = cnew; hsreg += hnew;
            const int gidx = (r0 + rl) * HH + m0 + mj;
            st_devu(&c2n[gidx], packsplit(cnew));
            st_devu(&h2n[gidx], packsplit(hnew));
        }
    }

    hsum[(r0 + rl) * HH + m0 + mj] = hsreg;
}

// Tail: sub = relu(tfidf@fcw+b); x = [sub | hsum/512]; 3-layer MLP (fp32).
__global__ void __launch_bounds__(256)
tail_kernel(const float* __restrict__ tfidf, const float* __restrict__ hsum,
            const float* __restrict__ fcw, const float* __restrict__ fcb,
            const float* __restrict__ l1w, const float* __restrict__ l1b,
            const float* __restrict__ l2w, const float* __restrict__ l2b,
            const float* __restrict__ low, const float* __restrict__ lob,
            float* __restrict__ out)
{
    const int row = blockIdx.x;
    const int t = threadIdx.x;
    __shared__ float tf[800];
    __shared__ float xrow[1024];
    __shared__ float y1[256];
    __shared__ float y2[128];

    for (int k = t; k < NTF; k += 256) tf[k] = tfidf[row * NTF + k];
    __syncthreads();

    for (int n = t; n < 512; n += 256) {
        float acc = fcb[n];
        for (int k = 0; k < NTF; ++k) acc += tf[k] * fcw[k * 512 + n];
        xrow[n] = fmaxf(acc, 0.f);
    }
    for (int n = t; n < 512; n += 256)
        xrow[512 + n] = hsum[row * HH + n] * (1.0f / 512.0f);
    __syncthreads();

    {
        float acc = l1b[t];
        for (int k = 0; k < 1024; ++k) acc += xrow[k] * l1w[k * 256 + t];
        y1[t] = fmaxf(acc, 0.f);
    }
    __syncthreads();
    if (t < 128) {
        float acc = l2b[t];
        for (int k = 0; k < 256; ++k) acc += y1[k] * l2w[k * 128 + t];
        y2[t] = fmaxf(acc, 0.f);
    }
    __syncthreads();
    if (t < 2) {
        float acc = lob[t];
        for (int k = 0; k < 128; ++k) acc += y2[k] * low[k * 2 + t];
        out[row * 2 + t] = acc;
    }
}

extern "C" void kernel_launch(void* const* d_in, const int* in_sizes, int n_in,
                              void* d_out, int out_size, void* d_ws, size_t ws_size,
                              hipStream_t stream)
{
    const float* x     = (const float*)d_in[0];
    const float* ts    = (const float*)d_in[1];
    const float* tfidf = (const float*)d_in[2];
    const float* Wall  = (const float*)d_in[3];
    const float* ball  = (const float*)d_in[4];
    const float* Uall  = (const float*)d_in[5];
    const float* bu    = (const float*)d_in[6];
    const float* Wd    = (const float*)d_in[7];
    const float* bd    = (const float*)d_in[8];
    const float* fcw   = (const float*)d_in[9];
    const float* fcb   = (const float*)d_in[10];
    const float* l1w   = (const float*)d_in[11];
    const float* l1b   = (const float*)d_in[12];
    const float* l2w   = (const float*)d_in[13];
    const float* l2b   = (const float*)d_in[14];
    const float* low   = (const float*)d_in[15];
    const float* lob   = (const float*)d_in[16];
    float* out = (float*)d_out;

    unsigned* wsu = (unsigned*)d_ws;
    unsigned* h2a = wsu;
    unsigned* h2b = h2a + BB * HH;
    unsigned* c2a = h2b + BB * HH;
    unsigned* c2b = c2a + BB * HH;
    float* hs  = (float*)(c2b + BB * HH);
    float* tsT = hs + BB * HH;
    unsigned* bar = (unsigned*)(tsT + BB * SS);
    unsigned short* B1 = (unsigned short*)(bar + 64);
    unsigned short* B2 = B1 + (size_t)32 * 32 * 4 * 2 * 64 * 8;  // B1 = 16.8MB

    prep_split<<<1152, 256, 0, stream>>>(Wall, Uall, Wd, B1, B2);

    void* args[] = { (void*)&x, (void*)&ts, (void*)&ball, (void*)&bu, (void*)&bd,
                     (void*)&B1, (void*)&B2,
                     (void*)&h2a, (void*)&h2b, (void*)&c2a, (void*)&c2b,
                     (void*)&hs, (void*)&tsT, (void*)&bar };
    hipLaunchCooperativeKernel((void*)lstm_persistent, dim3(256), dim3(512), args, 0, stream);

    tail_kernel<<<256, 256, 0, stream>>>(tfidf, hs, fcw, fcb, l1w, l1b, l2w, l2b,
                                         low, lob, out);
}